// Round 6
// baseline (2339.320 us; speedup 1.0000x reference)
//
#include <hip/hip_runtime.h>
#include <hip/hip_bf16.h>
#include <math.h>

#define NA 50000
#define NS 5000
#define E_AA 500000
#define E_AS 250000
#define CDIM 128
#define ED 8
#define NAPAD 50048   // 782*64

typedef __attribute__((ext_vector_type(8))) short bf16x8;
typedef __attribute__((ext_vector_type(4))) float f32x4;

__device__ inline short f2bf(float f) {
    __hip_bfloat16 h = __float2bfloat16(f);
    return *(short*)&h;
}
__device__ inline float bf2f(short s) {
    union { unsigned int u; float f; } cv;
    cv.u = ((unsigned int)(unsigned short)s) << 16;
    return cv.f;
}

// ---------------- small helpers ----------------

__device__ inline float4 f4fma(float s, float4 a, float4 b) {
    return make_float4(fmaf(s, a.x, b.x), fmaf(s, a.y, b.y),
                       fmaf(s, a.z, b.z), fmaf(s, a.w, b.w));
}
__device__ inline float4 f4add(float4 a, float4 b) {
    return make_float4(a.x + b.x, a.y + b.y, a.z + b.z, a.w + b.w);
}
__device__ inline float4 f4leaky(float4 a) {
    return make_float4(a.x > 0.f ? a.x : 0.2f * a.x, a.y > 0.f ? a.y : 0.2f * a.y,
                       a.z > 0.f ? a.z : 0.2f * a.z, a.w > 0.f ? a.w : 0.2f * a.w);
}
__device__ inline float f4dot(float4 a, float4 b) {
    return a.x * b.x + a.y * b.y + a.z * b.z + a.w * b.w;
}
__device__ inline float4 f4mix(float sc, float4 a, float p, float4 x) {
    return make_float4(fmaf(sc, a.x, p * x.x), fmaf(sc, a.y, p * x.y),
                       fmaf(sc, a.z, p * x.z), fmaf(sc, a.w, p * x.w));
}

// ---------------- CSR build ----------------

__global__ void count_k(const int* __restrict__ dst, int E, int* __restrict__ deg) {
    int e = blockIdx.x * blockDim.x + threadIdx.x;
    if (e < E) atomicAdd(&deg[dst[e]], 1);
}

__global__ __launch_bounds__(1024) void scan_k(const int* __restrict__ deg,
                                               int* __restrict__ row_start, int n) {
    int t = threadIdx.x;
    int per = (n + 1023) / 1024;
    int s0 = t * per;
    int s1 = s0 + per; if (s1 > n) s1 = n;
    int sum = 0;
    for (int i = s0; i < s1; ++i) sum += deg[i];
    __shared__ int wsum[16];
    int lane = t & 63, w = t >> 6;
    int v = sum;
    #pragma unroll
    for (int off = 1; off < 64; off <<= 1) {
        int u = __shfl_up(v, off, 64);
        if (lane >= off) v += u;
    }
    if (lane == 63) wsum[w] = v;
    __syncthreads();
    if (w == 0 && lane < 16) {
        int wv = wsum[lane];
        #pragma unroll
        for (int off = 1; off < 16; off <<= 1) {
            int u = __shfl_up(wv, off, 64);
            if (lane >= off) wv += u;
        }
        wsum[lane] = wv;
    }
    __syncthreads();
    int waveoff = (w > 0) ? wsum[w - 1] : 0;
    int excl = waveoff + v - sum;
    int run = excl;
    for (int i = s0; i < s1; ++i) { row_start[i] = run; run += deg[i]; }
    if (t == 1023) row_start[n] = run;
}

__global__ void scatter_k(const int* __restrict__ dst, int E,
                          const int* __restrict__ row_start,
                          int* __restrict__ cursor, int* __restrict__ csr) {
    int e = blockIdx.x * blockDim.x + threadIdx.x;
    if (e < E) {
        int d = dst[e];
        int pos = atomicAdd(&cursor[d], 1);
        csr[row_start[d] + pos] = e;
    }
}

// ---- degree counting-sort, two-level (LDS hist) ----

__global__ __launch_bounds__(256) void deghist_k(const int* __restrict__ rs, int n,
                                                 int* __restrict__ hist) {
    __shared__ int lh[256];
    int t = threadIdx.x;
    lh[t] = 0;
    __syncthreads();
    int d = blockIdx.x * 256 + t;
    if (d < n) {
        int deg = rs[d + 1] - rs[d];
        if (deg > 255) deg = 255;
        atomicAdd(&lh[deg], 1);
    }
    __syncthreads();
    if (lh[t]) atomicAdd(&hist[t], lh[t]);
}

__global__ __launch_bounds__(256) void degscatter_k(const int* __restrict__ rs, int n,
                                                    const int* __restrict__ binoff,
                                                    int* __restrict__ cursor,
                                                    int* __restrict__ perm) {
    __shared__ int lh[256];
    __shared__ int lbase[256];
    int t = threadIdx.x;
    lh[t] = 0;
    __syncthreads();
    int d = blockIdx.x * 256 + t;
    int deg = 0, lpos = 0;
    if (d < n) {
        deg = rs[d + 1] - rs[d];
        if (deg > 255) deg = 255;
        lpos = atomicAdd(&lh[deg], 1);
    }
    __syncthreads();
    int cnt = lh[t];
    if (cnt) lbase[t] = atomicAdd(&cursor[t], cnt);
    __syncthreads();
    if (d < n) perm[binoff[deg] + lbase[deg] + lpos] = d;
}

// ---------------- f32 -> bf16 convert (layer 0 X) ----------------

__global__ __launch_bounds__(256) void cvt_k(const float* __restrict__ in,
                                             short* __restrict__ out, int n4) {
    int i = blockIdx.x * 256 + threadIdx.x;
    if (i < n4) {
        float4 v = ((const float4*)in)[i];
        short4 s;
        s.x = f2bf(v.x); s.y = f2bf(v.y); s.z = f2bf(v.z); s.w = f2bf(v.w);
        ((short4*)out)[i] = s;
    }
}

// ---------------- W transpose+convert: Wt[w][n][k] bf16 ----------------

__global__ __launch_bounds__(256) void wtr_k(const float* __restrict__ W0,
                                             const float* __restrict__ W1,
                                             const float* __restrict__ W2,
                                             short* __restrict__ Wt) {
    int w = blockIdx.x >> 6;
    int idx = (blockIdx.x & 63) * 256 + threadIdx.x;  // 0..16383
    int k = idx >> 7, n = idx & 127;
    const float* W = (w == 0) ? W0 : ((w == 1) ? W1 : W2);
    Wt[w * 16384 + n * 128 + k] = f2bf(W[idx]);
}

// ---------------- MFMA triple GEMM ----------------
// Y0 (xl_aa) bf16, Y1 (xr_aa) f32, Y2 (xl_as) bf16.

__global__ __launch_bounds__(256) void gemm3_mfma_k(
    const short* __restrict__ Xb, const short* __restrict__ Wt,
    short* __restrict__ Y0b, float* __restrict__ Y1, short* __restrict__ Y2b, int N) {
    int t = threadIdx.x;
    int wave = t >> 6, lane = t & 63;
    int quad = lane >> 4, l16 = lane & 15;
    int rbase = blockIdx.x * 64 + wave * 16;

    bf16x8 a[4];
    const short* arow = Xb + (size_t)(rbase + l16) * 128 + quad * 8;
    #pragma unroll
    for (int kb = 0; kb < 4; ++kb) a[kb] = *(const bf16x8*)(arow + kb * 32);

    #pragma unroll
    for (int w = 0; w < 3; ++w) {
        const short* Wb = Wt + (size_t)w * 16384;
        #pragma unroll
        for (int nt = 0; nt < 8; ++nt) {
            f32x4 acc = {0.f, 0.f, 0.f, 0.f};
            const short* brow = Wb + (size_t)(nt * 16 + l16) * 128 + quad * 8;
            #pragma unroll
            for (int kb = 0; kb < 4; ++kb) {
                bf16x8 b = *(const bf16x8*)(brow + kb * 32);
                acc = __builtin_amdgcn_mfma_f32_16x16x32_bf16(a[kb], b, acc, 0, 0, 0);
            }
            int col = nt * 16 + l16;
            #pragma unroll
            for (int r = 0; r < 4; ++r) {
                int row = rbase + quad * 4 + r;
                if (row < N) {
                    if (w == 1) Y1[(size_t)row * 128 + col] = acc[r];
                    else if (w == 0) Y0b[(size_t)row * 128 + col] = f2bf(acc[r]);
                    else Y2b[(size_t)row * 128 + col] = f2bf(acc[r]);
                }
            }
        }
    }
}

// ---------------- single GEMM (style path): Y[N,128] = X[N,K] @ W[K,128] ----------------

template<int K>
__global__ __launch_bounds__(256) void gemm_k(const float* __restrict__ X,
                                              const float* __restrict__ W,
                                              float* __restrict__ Y, int N) {
    __shared__ float Ws[64 * 128];
    __shared__ float Xs[32 * (K + 4)];
    const int XS = K + 4;
    int t = threadIdx.x;
    int rbase = blockIdx.x * 32;

    const int K4 = K / 4;
    const float4* X4 = (const float4*)X;
    for (int i = t; i < 32 * K4; i += 256) {
        int r = i / K4, c4 = i % K4;
        int row = rbase + r;
        float4 v = make_float4(0.f, 0.f, 0.f, 0.f);
        if (row < N) v = X4[(size_t)row * K4 + c4];
        *(float4*)(Xs + r * XS + c4 * 4) = v;
    }

    int cg = t & 31;
    int rq = t >> 5;
    float4 acc[4] = {};
    float4* Ws4 = (float4*)Ws;
    const float4* W4 = (const float4*)W;

    for (int kb = 0; kb < K; kb += 64) {
        __syncthreads();
        for (int i = t; i < 2048; i += 256) Ws4[i] = W4[(size_t)kb * 32 + i];
        __syncthreads();
        #pragma unroll 8
        for (int k2 = 0; k2 < 64; ++k2) {
            float4 w = Ws4[k2 * 32 + cg];
            int k = kb + k2;
            #pragma unroll
            for (int i = 0; i < 4; ++i) {
                float x = Xs[(rq + 8 * i) * XS + k];
                acc[i].x += x * w.x; acc[i].y += x * w.y;
                acc[i].z += x * w.z; acc[i].w += x * w.w;
            }
        }
    }
    #pragma unroll
    for (int i = 0; i < 4; ++i) {
        int row = rbase + rq + 8 * i;
        if (row < N) ((float4*)Y)[(size_t)row * 32 + cg] = acc[i];
    }
}

// ---------------- fused GATv2 aggregation: 4 dst/wave, 16 lanes/dst ----------------
// xl gathered in bf16 (half traffic); optional f32 out and bf16 outb.

template<bool RELU>
__global__ __launch_bounds__(256, 4) void agg_k(
    const short* __restrict__ xl, const float* __restrict__ xr,
    const float* __restrict__ eattr, const int* __restrict__ srcv,
    const float* __restrict__ We, const float* __restrict__ att,
    const float* __restrict__ bias, const int* __restrict__ row_start,
    const int* __restrict__ csr_eid, const int* __restrict__ perm,
    float* __restrict__ out, short* __restrict__ outb, int ndst, int Etot) {
    int wave = threadIdx.x >> 6;
    int lane = threadIdx.x & 63;
    int g = lane >> 4;
    int sl = lane & 15;
    int c = sl * 8;

    int di = blockIdx.x * 16 + wave * 4 + g;
    bool has = di < ndst;
    int d = has ? perm[di] : 0;

    float4 WeA[8], WeB[8];
    #pragma unroll
    for (int k = 0; k < 8; ++k) {
        WeA[k] = *(const float4*)(We + k * 128 + c);
        WeB[k] = *(const float4*)(We + k * 128 + c + 4);
    }
    float4 attA = *(const float4*)(att + c);
    float4 attB = *(const float4*)(att + c + 4);
    float4 bA = *(const float4*)(bias + c);
    float4 bB = *(const float4*)(bias + c + 4);
    float4 xrA = *(const float4*)(xr + (size_t)d * 128 + c);
    float4 xrB = *(const float4*)(xr + (size_t)d * 128 + c + 4);

    float4 accA = {0,0,0,0}, accB = {0,0,0,0};
    float den = 0.f, mrun = -INFINITY;

    int e0 = has ? row_start[d] : 0;
    int cnt = has ? row_start[d + 1] - e0 : 0;

    for (int i = 0; ; i += 4) {
        if (!__any(i < cnt)) break;

        int idx0 = e0 + i;
        int c0 = idx0 < Etot ? idx0 : Etot - 1;
        int c1 = idx0 + 1 < Etot ? idx0 + 1 : Etot - 1;
        int c2 = idx0 + 2 < Etot ? idx0 + 2 : Etot - 1;
        int c3 = idx0 + 3 < Etot ? idx0 + 3 : Etot - 1;
        int ei0 = csr_eid[c0], ei1 = csr_eid[c1], ei2 = csr_eid[c2], ei3 = csr_eid[c3];
        int s0 = srcv[ei0], s1 = srcv[ei1], s2 = srcv[ei2], s3 = srcv[ei3];

        bf16x8 xb0 = *(const bf16x8*)(xl + (size_t)s0 * 128 + c);
        bf16x8 xb1 = *(const bf16x8*)(xl + (size_t)s1 * 128 + c);
        bf16x8 xb2 = *(const bf16x8*)(xl + (size_t)s2 * 128 + c);
        bf16x8 xb3 = *(const bf16x8*)(xl + (size_t)s3 * 128 + c);
        const float4* q0 = (const float4*)(eattr + (size_t)ei0 * 8);
        const float4* q1 = (const float4*)(eattr + (size_t)ei1 * 8);
        const float4* q2 = (const float4*)(eattr + (size_t)ei2 * 8);
        const float4* q3 = (const float4*)(eattr + (size_t)ei3 * 8);
        float4 e0a = q0[0], e0b = q0[1];
        float4 e1a = q1[0], e1b = q1[1];
        float4 e2a = q2[0], e2b = q2[1];
        float4 e3a = q3[0], e3b = q3[1];

        float4 x0A = make_float4(bf2f(xb0[0]), bf2f(xb0[1]), bf2f(xb0[2]), bf2f(xb0[3]));
        float4 x0B = make_float4(bf2f(xb0[4]), bf2f(xb0[5]), bf2f(xb0[6]), bf2f(xb0[7]));
        float4 x1A = make_float4(bf2f(xb1[0]), bf2f(xb1[1]), bf2f(xb1[2]), bf2f(xb1[3]));
        float4 x1B = make_float4(bf2f(xb1[4]), bf2f(xb1[5]), bf2f(xb1[6]), bf2f(xb1[7]));
        float4 x2A = make_float4(bf2f(xb2[0]), bf2f(xb2[1]), bf2f(xb2[2]), bf2f(xb2[3]));
        float4 x2B = make_float4(bf2f(xb2[4]), bf2f(xb2[5]), bf2f(xb2[6]), bf2f(xb2[7]));
        float4 x3A = make_float4(bf2f(xb3[0]), bf2f(xb3[1]), bf2f(xb3[2]), bf2f(xb3[3]));
        float4 x3B = make_float4(bf2f(xb3[4]), bf2f(xb3[5]), bf2f(xb3[6]), bf2f(xb3[7]));

        auto logit = [&](float4 xA, float4 xB, float4 ea, float4 eb) -> float {
            float4 mA = f4add(xA, xrA), mB = f4add(xB, xrB);
            mA = f4fma(ea.x, WeA[0], mA); mB = f4fma(ea.x, WeB[0], mB);
            mA = f4fma(ea.y, WeA[1], mA); mB = f4fma(ea.y, WeB[1], mB);
            mA = f4fma(ea.z, WeA[2], mA); mB = f4fma(ea.z, WeB[2], mB);
            mA = f4fma(ea.w, WeA[3], mA); mB = f4fma(ea.w, WeB[3], mB);
            mA = f4fma(eb.x, WeA[4], mA); mB = f4fma(eb.x, WeB[4], mB);
            mA = f4fma(eb.y, WeA[5], mA); mB = f4fma(eb.y, WeB[5], mB);
            mA = f4fma(eb.z, WeA[6], mA); mB = f4fma(eb.z, WeB[6], mB);
            mA = f4fma(eb.w, WeA[7], mA); mB = f4fma(eb.w, WeB[7], mB);
            return f4dot(f4leaky(mA), attA) + f4dot(f4leaky(mB), attB);
        };

        float t0 = logit(x0A, x0B, e0a, e0b);
        float t1 = logit(x1A, x1B, e1a, e1b);
        float t2 = logit(x2A, x2B, e2a, e2b);
        float t3 = logit(x3A, x3B, e3a, e3b);
        #pragma unroll
        for (int off = 8; off; off >>= 1) {
            t0 += __shfl_xor(t0, off, 64);
            t1 += __shfl_xor(t1, off, 64);
            t2 += __shfl_xor(t2, off, 64);
            t3 += __shfl_xor(t3, off, 64);
        }

        if (i + 0 < cnt) {
            float nm = fmaxf(mrun, t0); float sc = __expf(mrun - nm); float p = __expf(t0 - nm);
            den = den * sc + p; accA = f4mix(sc, accA, p, x0A); accB = f4mix(sc, accB, p, x0B); mrun = nm;
        }
        if (i + 1 < cnt) {
            float nm = fmaxf(mrun, t1); float sc = __expf(mrun - nm); float p = __expf(t1 - nm);
            den = den * sc + p; accA = f4mix(sc, accA, p, x1A); accB = f4mix(sc, accB, p, x1B); mrun = nm;
        }
        if (i + 2 < cnt) {
            float nm = fmaxf(mrun, t2); float sc = __expf(mrun - nm); float p = __expf(t2 - nm);
            den = den * sc + p; accA = f4mix(sc, accA, p, x2A); accB = f4mix(sc, accB, p, x2B); mrun = nm;
        }
        if (i + 3 < cnt) {
            float nm = fmaxf(mrun, t3); float sc = __expf(mrun - nm); float p = __expf(t3 - nm);
            den = den * sc + p; accA = f4mix(sc, accA, p, x3A); accB = f4mix(sc, accB, p, x3B); mrun = nm;
        }
    }

    float inv = 1.f / fmaxf(den, 1e-16f);
    float4 oA = make_float4(accA.x * inv + bA.x, accA.y * inv + bA.y,
                            accA.z * inv + bA.z, accA.w * inv + bA.w);
    float4 oB = make_float4(accB.x * inv + bB.x, accB.y * inv + bB.y,
                            accB.z * inv + bB.z, accB.w * inv + bB.w);
    if (RELU) {
        oA = make_float4(fmaxf(oA.x,0.f), fmaxf(oA.y,0.f), fmaxf(oA.z,0.f), fmaxf(oA.w,0.f));
        oB = make_float4(fmaxf(oB.x,0.f), fmaxf(oB.y,0.f), fmaxf(oB.z,0.f), fmaxf(oB.w,0.f));
    }
    float ss = f4dot(oA, oA) + f4dot(oB, oB);
    #pragma unroll
    for (int off = 8; off; off >>= 1) ss += __shfl_xor(ss, off, 64);
    float innv = 1.f / fmaxf(sqrtf(ss), 1e-12f);
    oA = make_float4(oA.x * innv, oA.y * innv, oA.z * innv, oA.w * innv);
    oB = make_float4(oB.x * innv, oB.y * innv, oB.z * innv, oB.w * innv);
    if (has) {
        if (out) {
            float4* op = (float4*)(out + (size_t)d * 128 + c);
            op[0] = oA;
            op[1] = oB;
        }
        if (outb) {
            bf16x8 pk;
            pk[0] = f2bf(oA.x); pk[1] = f2bf(oA.y); pk[2] = f2bf(oA.z); pk[3] = f2bf(oA.w);
            pk[4] = f2bf(oB.x); pk[5] = f2bf(oB.y); pk[6] = f2bf(oB.z); pk[7] = f2bf(oB.w);
            *(bf16x8*)(outb + (size_t)d * 128 + c) = pk;
        }
    }
}

// ---------------- launch ----------------

extern "C" void kernel_launch(void* const* d_in, const int* in_sizes, int n_in,
                              void* d_out, int out_size, void* d_ws, size_t ws_size,
                              hipStream_t stream) {
    const float* x_artist = (const float*)d_in[0];
    const float* x_style  = (const float*)d_in[1];
    const int*   src_aa   = (const int*)d_in[2];
    const int*   dst_aa   = (const int*)d_in[3];
    const float* eattr_aa = (const float*)d_in[4];
    const int*   src_as   = (const int*)d_in[5];
    const int*   dst_as   = (const int*)d_in[6];
    const float* eattr_as = (const float*)d_in[7];
    const float* Wl0_aa = (const float*)d_in[8];
    const float* Wr0_aa = (const float*)d_in[9];
    const float* att0_aa = (const float*)d_in[10];
    const float* We0_aa = (const float*)d_in[11];
    const float* b0_aa = (const float*)d_in[12];
    const float* Wl0_as = (const float*)d_in[13];
    const float* Wr0_as = (const float*)d_in[14];
    const float* att0_as = (const float*)d_in[15];
    const float* We0_as = (const float*)d_in[16];
    const float* b0_as = (const float*)d_in[17];
    const float* Wl_aa = (const float*)d_in[18];
    const float* Wr_aa = (const float*)d_in[19];
    const float* att_aa = (const float*)d_in[20];
    const float* We_aa = (const float*)d_in[21];
    const float* b_aa = (const float*)d_in[22];
    const float* Wl_as = (const float*)d_in[23];
    const float* Wr_as = (const float*)d_in[24];
    const float* att_as = (const float*)d_in[25];
    const float* We_as = (const float*)d_in[26];
    const float* b_as = (const float*)d_in[27];

    float* out = (float*)d_out;

    // ws layout: bf16 regions first, then floats, then ints
    short* Xb    = (short*)d_ws;                    // [NAPAD][128]
    short* Wt    = Xb + (size_t)NAPAD * 128;        // [3][128][128]
    short* bufAb = Wt + 3 * 16384;                  // xl_aa bf16
    short* bufDb = bufAb + (size_t)NA * 128;        // xl_as bf16
    float* fbase = (float*)(bufDb + (size_t)NA * 128);
    size_t off = 0;
    auto allocf = [&](size_t n) { float* r = fbase + off; off += n; return r; };
    float* hS0 = allocf((size_t)NS * CDIM);
    float* hS1 = allocf((size_t)NS * CDIM);
    float* bufB = allocf((size_t)NA * CDIM);   // xr_aa f32
    float* bufC = allocf((size_t)NS * CDIM);   // xr_as f32
    int* ip = (int*)(fbase + off);
    int* rs_aa  = ip;            ip += NA + 1;
    int* cur_aa = ip;            ip += NA;
    int* csr_aa = ip;            ip += E_AA;
    int* rs_as  = ip;            ip += NS + 1;
    int* cur_as = ip;            ip += NS;
    int* csr_as = ip;            ip += E_AS;
    int* perm_aa = ip;           ip += NA;
    int* perm_as = ip;           ip += NS;
    int* dh   = ip;              ip += 256;
    int* dbo  = ip;              ip += 257;
    int* dcur = ip;              ip += 256;

    // ---- CSR + degree-sorted perm, AA ----
    hipMemsetAsync(cur_aa, 0, NA * sizeof(int), stream);
    count_k<<<(E_AA + 255) / 256, 256, 0, stream>>>(dst_aa, E_AA, cur_aa);
    scan_k<<<1, 1024, 0, stream>>>(cur_aa, rs_aa, NA);
    hipMemsetAsync(cur_aa, 0, NA * sizeof(int), stream);
    scatter_k<<<(E_AA + 255) / 256, 256, 0, stream>>>(dst_aa, E_AA, rs_aa, cur_aa, csr_aa);
    hipMemsetAsync(dh, 0, 256 * sizeof(int), stream);
    hipMemsetAsync(dcur, 0, 256 * sizeof(int), stream);
    deghist_k<<<(NA + 255) / 256, 256, 0, stream>>>(rs_aa, NA, dh);
    scan_k<<<1, 1024, 0, stream>>>(dh, dbo, 256);
    degscatter_k<<<(NA + 255) / 256, 256, 0, stream>>>(rs_aa, NA, dbo, dcur, perm_aa);

    // ---- CSR + degree-sorted perm, AS ----
    hipMemsetAsync(cur_as, 0, NS * sizeof(int), stream);
    count_k<<<(E_AS + 255) / 256, 256, 0, stream>>>(dst_as, E_AS, cur_as);
    scan_k<<<1, 1024, 0, stream>>>(cur_as, rs_as, NS);
    hipMemsetAsync(cur_as, 0, NS * sizeof(int), stream);
    scatter_k<<<(E_AS + 255) / 256, 256, 0, stream>>>(dst_as, E_AS, rs_as, cur_as, csr_as);
    hipMemsetAsync(dh, 0, 256 * sizeof(int), stream);
    hipMemsetAsync(dcur, 0, 256 * sizeof(int), stream);
    deghist_k<<<(NS + 255) / 256, 256, 0, stream>>>(rs_as, NS, dh);
    scan_k<<<1, 1024, 0, stream>>>(dh, dbo, 256);
    degscatter_k<<<(NS + 255) / 256, 256, 0, stream>>>(rs_as, NS, dbo, dcur, perm_as);

    // layer-0 X -> bf16
    cvt_k<<<(NA * CDIM / 4 + 255) / 256, 256, 0, stream>>>(x_artist, Xb, NA * CDIM / 4);

    const int gM = NAPAD / 64;
    const int gS = (NS + 31) / 32;
    const int aggA = (NA + 15) / 16;
    const int aggS = (NS + 15) / 16;

    const float* hS_in = x_style;

    for (int layer = 0; layer < 3; ++layer) {
        int j = layer - 1;
        const float *pWl_aa, *pWr_aa, *patt_aa, *pWe_aa, *pb_aa;
        const float *pWl_as, *pWr_as, *patt_as, *pWe_as, *pb_as;
        if (layer == 0) {
            pWl_aa = Wl0_aa; pWr_aa = Wr0_aa; patt_aa = att0_aa; pWe_aa = We0_aa; pb_aa = b0_aa;
            pWl_as = Wl0_as; pWr_as = Wr0_as; patt_as = att0_as; pWe_as = We0_as; pb_as = b0_as;
        } else {
            pWl_aa = Wl_aa + (size_t)j * CDIM * CDIM;
            pWr_aa = Wr_aa + (size_t)j * CDIM * CDIM;
            patt_aa = att_aa + (size_t)j * CDIM;
            pWe_aa = We_aa + (size_t)j * ED * CDIM;
            pb_aa = b_aa + (size_t)j * CDIM;
            pWl_as = Wl_as + (size_t)j * CDIM * CDIM;
            pWr_as = Wr_as + (size_t)j * CDIM * CDIM;
            patt_as = att_as + (size_t)j * CDIM;
            pWe_as = We_as + (size_t)j * ED * CDIM;
            pb_as = b_as + (size_t)j * CDIM;
        }
        // f32 hA output only needed at the final layer
        float* hA_out = (layer == 2) ? out : nullptr;
        float* hS_out = (layer == 2) ? out + (size_t)NA * CDIM : (layer == 0 ? hS0 : hS1);
        short* hA_outb = (layer == 2) ? nullptr : Xb;

        wtr_k<<<3 * 64, 256, 0, stream>>>(pWl_aa, pWr_aa, pWl_as, Wt);

        gemm3_mfma_k<<<gM, 256, 0, stream>>>(Xb, Wt, bufAb, bufB, bufDb, NA);
        if (layer == 0)
            gemm_k<64><<<gS, 256, 0, stream>>>(hS_in, pWr_as, bufC, NS);
        else
            gemm_k<128><<<gS, 256, 0, stream>>>(hS_in, pWr_as, bufC, NS);

        if (layer < 2) {
            agg_k<true><<<aggA, 256, 0, stream>>>(bufAb, bufB, eattr_aa, src_aa, pWe_aa,
                                                  patt_aa, pb_aa, rs_aa, csr_aa, perm_aa,
                                                  hA_out, hA_outb, NA, E_AA);
            agg_k<true><<<aggS, 256, 0, stream>>>(bufDb, bufC, eattr_as, src_as, pWe_as,
                                                  patt_as, pb_as, rs_as, csr_as, perm_as,
                                                  hS_out, nullptr, NS, E_AS);
        } else {
            agg_k<false><<<aggA, 256, 0, stream>>>(bufAb, bufB, eattr_aa, src_aa, pWe_aa,
                                                   patt_aa, pb_aa, rs_aa, csr_aa, perm_aa,
                                                   hA_out, nullptr, NA, E_AA);
            agg_k<false><<<aggS, 256, 0, stream>>>(bufDb, bufC, eattr_as, src_as, pWe_as,
                                                   patt_as, pb_as, rs_as, csr_as, perm_as,
                                                   hS_out, nullptr, NS, E_AS);
        }

        hS_in = hS_out;
    }
}

// Round 7
// 914.254 us; speedup vs baseline: 2.5587x; 2.5587x over previous
//
#include <hip/hip_runtime.h>
#include <hip/hip_bf16.h>
#include <math.h>

#define NA 50000
#define NS 5000
#define E_AA 500000
#define E_AS 250000
#define CDIM 128
#define ED 8
#define NAPAD 50048   // 782*64

typedef __attribute__((ext_vector_type(8))) short bf16x8;
typedef __attribute__((ext_vector_type(4))) float f32x4;

__device__ inline short f2bf(float f) {
    __hip_bfloat16 h = __float2bfloat16(f);
    return *(short*)&h;
}
__device__ inline float bf2f(short s) {
    union { unsigned int u; float f; } cv;
    cv.u = ((unsigned int)(unsigned short)s) << 16;
    return cv.f;
}

// ---------------- small helpers ----------------

__device__ inline float4 f4fma(float s, float4 a, float4 b) {
    return make_float4(fmaf(s, a.x, b.x), fmaf(s, a.y, b.y),
                       fmaf(s, a.z, b.z), fmaf(s, a.w, b.w));
}
__device__ inline float4 f4add(float4 a, float4 b) {
    return make_float4(a.x + b.x, a.y + b.y, a.z + b.z, a.w + b.w);
}
__device__ inline float4 f4leaky(float4 a) {
    return make_float4(a.x > 0.f ? a.x : 0.2f * a.x, a.y > 0.f ? a.y : 0.2f * a.y,
                       a.z > 0.f ? a.z : 0.2f * a.z, a.w > 0.f ? a.w : 0.2f * a.w);
}
__device__ inline float f4dot(float4 a, float4 b) {
    return a.x * b.x + a.y * b.y + a.z * b.z + a.w * b.w;
}
__device__ inline float4 f4mix(float sc, float4 a, float p, float4 x) {
    return make_float4(fmaf(sc, a.x, p * x.x), fmaf(sc, a.y, p * x.y),
                       fmaf(sc, a.z, p * x.z), fmaf(sc, a.w, p * x.w));
}

// ---------------- CSR build ----------------

__global__ void count_k(const int* __restrict__ dst, int E, int* __restrict__ deg) {
    int e = blockIdx.x * blockDim.x + threadIdx.x;
    if (e < E) atomicAdd(&deg[dst[e]], 1);
}

__global__ __launch_bounds__(1024) void scan_k(const int* __restrict__ deg,
                                               int* __restrict__ row_start, int n) {
    int t = threadIdx.x;
    int per = (n + 1023) / 1024;
    int s0 = t * per;
    int s1 = s0 + per; if (s1 > n) s1 = n;
    int sum = 0;
    for (int i = s0; i < s1; ++i) sum += deg[i];
    __shared__ int wsum[16];
    int lane = t & 63, w = t >> 6;
    int v = sum;
    #pragma unroll
    for (int off = 1; off < 64; off <<= 1) {
        int u = __shfl_up(v, off, 64);
        if (lane >= off) v += u;
    }
    if (lane == 63) wsum[w] = v;
    __syncthreads();
    if (w == 0 && lane < 16) {
        int wv = wsum[lane];
        #pragma unroll
        for (int off = 1; off < 16; off <<= 1) {
            int u = __shfl_up(wv, off, 64);
            if (lane >= off) wv += u;
        }
        wsum[lane] = wv;
    }
    __syncthreads();
    int waveoff = (w > 0) ? wsum[w - 1] : 0;
    int excl = waveoff + v - sum;
    int run = excl;
    for (int i = s0; i < s1; ++i) { row_start[i] = run; run += deg[i]; }
    if (t == 1023) row_start[n] = run;
}

__global__ void scatter_k(const int* __restrict__ dst, int E,
                          const int* __restrict__ row_start,
                          int* __restrict__ cursor, int* __restrict__ csr) {
    int e = blockIdx.x * blockDim.x + threadIdx.x;
    if (e < E) {
        int d = dst[e];
        int pos = atomicAdd(&cursor[d], 1);
        csr[row_start[d] + pos] = e;
    }
}

// ---- degree counting-sort, two-level (LDS hist) ----

__global__ __launch_bounds__(256) void deghist_k(const int* __restrict__ rs, int n,
                                                 int* __restrict__ hist) {
    __shared__ int lh[256];
    int t = threadIdx.x;
    lh[t] = 0;
    __syncthreads();
    int d = blockIdx.x * 256 + t;
    if (d < n) {
        int deg = rs[d + 1] - rs[d];
        if (deg > 255) deg = 255;
        atomicAdd(&lh[deg], 1);
    }
    __syncthreads();
    if (lh[t]) atomicAdd(&hist[t], lh[t]);
}

__global__ __launch_bounds__(256) void degscatter_k(const int* __restrict__ rs, int n,
                                                    const int* __restrict__ binoff,
                                                    int* __restrict__ cursor,
                                                    int* __restrict__ perm) {
    __shared__ int lh[256];
    __shared__ int lbase[256];
    int t = threadIdx.x;
    lh[t] = 0;
    __syncthreads();
    int d = blockIdx.x * 256 + t;
    int deg = 0, lpos = 0;
    if (d < n) {
        deg = rs[d + 1] - rs[d];
        if (deg > 255) deg = 255;
        lpos = atomicAdd(&lh[deg], 1);
    }
    __syncthreads();
    int cnt = lh[t];
    if (cnt) lbase[t] = atomicAdd(&cursor[t], cnt);
    __syncthreads();
    if (d < n) perm[binoff[deg] + lbase[deg] + lpos] = d;
}

// ---------------- f32 -> bf16 convert (layer 0 X) ----------------

__global__ __launch_bounds__(256) void cvt_k(const float* __restrict__ in,
                                             short* __restrict__ out, int n4) {
    int i = blockIdx.x * 256 + threadIdx.x;
    if (i < n4) {
        float4 v = ((const float4*)in)[i];
        short4 s;
        s.x = f2bf(v.x); s.y = f2bf(v.y); s.z = f2bf(v.z); s.w = f2bf(v.w);
        ((short4*)out)[i] = s;
    }
}

// ---------------- W transpose+convert: Wt[w][n][k] bf16 ----------------

__global__ __launch_bounds__(256) void wtr_k(const float* __restrict__ W0,
                                             const float* __restrict__ W1,
                                             const float* __restrict__ W2,
                                             short* __restrict__ Wt) {
    int w = blockIdx.x >> 6;
    int idx = (blockIdx.x & 63) * 256 + threadIdx.x;  // 0..16383
    int k = idx >> 7, n = idx & 127;
    const float* W = (w == 0) ? W0 : ((w == 1) ? W1 : W2);
    Wt[w * 16384 + n * 128 + k] = f2bf(W[idx]);
}

// ---------------- MFMA triple GEMM ----------------
// Y0 (xl_aa) bf16, Y1 (xr_aa) f32, Y2 (xl_as) bf16.

__global__ __launch_bounds__(256) void gemm3_mfma_k(
    const short* __restrict__ Xb, const short* __restrict__ Wt,
    short* __restrict__ Y0b, float* __restrict__ Y1, short* __restrict__ Y2b, int N) {
    int t = threadIdx.x;
    int wave = t >> 6, lane = t & 63;
    int quad = lane >> 4, l16 = lane & 15;
    int rbase = blockIdx.x * 64 + wave * 16;

    bf16x8 a[4];
    const short* arow = Xb + (size_t)(rbase + l16) * 128 + quad * 8;
    #pragma unroll
    for (int kb = 0; kb < 4; ++kb) a[kb] = *(const bf16x8*)(arow + kb * 32);

    #pragma unroll
    for (int w = 0; w < 3; ++w) {
        const short* Wb = Wt + (size_t)w * 16384;
        #pragma unroll
        for (int nt = 0; nt < 8; ++nt) {
            f32x4 acc = {0.f, 0.f, 0.f, 0.f};
            const short* brow = Wb + (size_t)(nt * 16 + l16) * 128 + quad * 8;
            #pragma unroll
            for (int kb = 0; kb < 4; ++kb) {
                bf16x8 b = *(const bf16x8*)(brow + kb * 32);
                acc = __builtin_amdgcn_mfma_f32_16x16x32_bf16(a[kb], b, acc, 0, 0, 0);
            }
            int col = nt * 16 + l16;
            #pragma unroll
            for (int r = 0; r < 4; ++r) {
                int row = rbase + quad * 4 + r;
                if (row < N) {
                    if (w == 1) Y1[(size_t)row * 128 + col] = acc[r];
                    else if (w == 0) Y0b[(size_t)row * 128 + col] = f2bf(acc[r]);
                    else Y2b[(size_t)row * 128 + col] = f2bf(acc[r]);
                }
            }
        }
    }
}

// ---------------- single GEMM (style path): Y[N,128] = X[N,K] @ W[K,128] ----------------

template<int K>
__global__ __launch_bounds__(256) void gemm_k(const float* __restrict__ X,
                                              const float* __restrict__ W,
                                              float* __restrict__ Y, int N) {
    __shared__ float Ws[64 * 128];
    __shared__ float Xs[32 * (K + 4)];
    const int XS = K + 4;
    int t = threadIdx.x;
    int rbase = blockIdx.x * 32;

    const int K4 = K / 4;
    const float4* X4 = (const float4*)X;
    for (int i = t; i < 32 * K4; i += 256) {
        int r = i / K4, c4 = i % K4;
        int row = rbase + r;
        float4 v = make_float4(0.f, 0.f, 0.f, 0.f);
        if (row < N) v = X4[(size_t)row * K4 + c4];
        *(float4*)(Xs + r * XS + c4 * 4) = v;
    }

    int cg = t & 31;
    int rq = t >> 5;
    float4 acc[4] = {};
    float4* Ws4 = (float4*)Ws;
    const float4* W4 = (const float4*)W;

    for (int kb = 0; kb < K; kb += 64) {
        __syncthreads();
        for (int i = t; i < 2048; i += 256) Ws4[i] = W4[(size_t)kb * 32 + i];
        __syncthreads();
        #pragma unroll 8
        for (int k2 = 0; k2 < 64; ++k2) {
            float4 w = Ws4[k2 * 32 + cg];
            int k = kb + k2;
            #pragma unroll
            for (int i = 0; i < 4; ++i) {
                float x = Xs[(rq + 8 * i) * XS + k];
                acc[i].x += x * w.x; acc[i].y += x * w.y;
                acc[i].z += x * w.z; acc[i].w += x * w.w;
            }
        }
    }
    #pragma unroll
    for (int i = 0; i < 4; ++i) {
        int row = rbase + rq + 8 * i;
        if (row < N) ((float4*)Y)[(size_t)row * 32 + cg] = acc[i];
    }
}

// ---------------- fused GATv2 aggregation: 4 dst/wave, 16 lanes/dst ----------------
// xl gathered in bf16 (half traffic); optional f32 out and bf16 outb.
// NOTE: launch_bounds (256,2) — (256,4) forces 128-VGPR cap -> spill -> 1.5 GB
// of scratch traffic per dispatch (R6 regression).

template<bool RELU>
__global__ __launch_bounds__(256, 2) void agg_k(
    const short* __restrict__ xl, const float* __restrict__ xr,
    const float* __restrict__ eattr, const int* __restrict__ srcv,
    const float* __restrict__ We, const float* __restrict__ att,
    const float* __restrict__ bias, const int* __restrict__ row_start,
    const int* __restrict__ csr_eid, const int* __restrict__ perm,
    float* __restrict__ out, short* __restrict__ outb, int ndst, int Etot) {
    int wave = threadIdx.x >> 6;
    int lane = threadIdx.x & 63;
    int g = lane >> 4;
    int sl = lane & 15;
    int c = sl * 8;

    int di = blockIdx.x * 16 + wave * 4 + g;
    bool has = di < ndst;
    int d = has ? perm[di] : 0;

    float4 WeA[8], WeB[8];
    #pragma unroll
    for (int k = 0; k < 8; ++k) {
        WeA[k] = *(const float4*)(We + k * 128 + c);
        WeB[k] = *(const float4*)(We + k * 128 + c + 4);
    }
    float4 attA = *(const float4*)(att + c);
    float4 attB = *(const float4*)(att + c + 4);
    float4 bA = *(const float4*)(bias + c);
    float4 bB = *(const float4*)(bias + c + 4);
    float4 xrA = *(const float4*)(xr + (size_t)d * 128 + c);
    float4 xrB = *(const float4*)(xr + (size_t)d * 128 + c + 4);

    float4 accA = {0,0,0,0}, accB = {0,0,0,0};
    float den = 0.f, mrun = -INFINITY;

    int e0 = has ? row_start[d] : 0;
    int cnt = has ? row_start[d + 1] - e0 : 0;

    for (int i = 0; ; i += 4) {
        if (!__any(i < cnt)) break;

        int idx0 = e0 + i;
        int c0 = idx0 < Etot ? idx0 : Etot - 1;
        int c1 = idx0 + 1 < Etot ? idx0 + 1 : Etot - 1;
        int c2 = idx0 + 2 < Etot ? idx0 + 2 : Etot - 1;
        int c3 = idx0 + 3 < Etot ? idx0 + 3 : Etot - 1;
        int ei0 = csr_eid[c0], ei1 = csr_eid[c1], ei2 = csr_eid[c2], ei3 = csr_eid[c3];
        int s0 = srcv[ei0], s1 = srcv[ei1], s2 = srcv[ei2], s3 = srcv[ei3];

        bf16x8 xb0 = *(const bf16x8*)(xl + (size_t)s0 * 128 + c);
        bf16x8 xb1 = *(const bf16x8*)(xl + (size_t)s1 * 128 + c);
        bf16x8 xb2 = *(const bf16x8*)(xl + (size_t)s2 * 128 + c);
        bf16x8 xb3 = *(const bf16x8*)(xl + (size_t)s3 * 128 + c);
        const float4* q0 = (const float4*)(eattr + (size_t)ei0 * 8);
        const float4* q1 = (const float4*)(eattr + (size_t)ei1 * 8);
        const float4* q2 = (const float4*)(eattr + (size_t)ei2 * 8);
        const float4* q3 = (const float4*)(eattr + (size_t)ei3 * 8);
        float4 e0a = q0[0], e0b = q0[1];
        float4 e1a = q1[0], e1b = q1[1];
        float4 e2a = q2[0], e2b = q2[1];
        float4 e3a = q3[0], e3b = q3[1];

        float4 x0A = make_float4(bf2f(xb0[0]), bf2f(xb0[1]), bf2f(xb0[2]), bf2f(xb0[3]));
        float4 x0B = make_float4(bf2f(xb0[4]), bf2f(xb0[5]), bf2f(xb0[6]), bf2f(xb0[7]));
        float4 x1A = make_float4(bf2f(xb1[0]), bf2f(xb1[1]), bf2f(xb1[2]), bf2f(xb1[3]));
        float4 x1B = make_float4(bf2f(xb1[4]), bf2f(xb1[5]), bf2f(xb1[6]), bf2f(xb1[7]));
        float4 x2A = make_float4(bf2f(xb2[0]), bf2f(xb2[1]), bf2f(xb2[2]), bf2f(xb2[3]));
        float4 x2B = make_float4(bf2f(xb2[4]), bf2f(xb2[5]), bf2f(xb2[6]), bf2f(xb2[7]));
        float4 x3A = make_float4(bf2f(xb3[0]), bf2f(xb3[1]), bf2f(xb3[2]), bf2f(xb3[3]));
        float4 x3B = make_float4(bf2f(xb3[4]), bf2f(xb3[5]), bf2f(xb3[6]), bf2f(xb3[7]));

        auto logit = [&](float4 xA, float4 xB, float4 ea, float4 eb) -> float {
            float4 mA = f4add(xA, xrA), mB = f4add(xB, xrB);
            mA = f4fma(ea.x, WeA[0], mA); mB = f4fma(ea.x, WeB[0], mB);
            mA = f4fma(ea.y, WeA[1], mA); mB = f4fma(ea.y, WeB[1], mB);
            mA = f4fma(ea.z, WeA[2], mA); mB = f4fma(ea.z, WeB[2], mB);
            mA = f4fma(ea.w, WeA[3], mA); mB = f4fma(ea.w, WeB[3], mB);
            mA = f4fma(eb.x, WeA[4], mA); mB = f4fma(eb.x, WeB[4], mB);
            mA = f4fma(eb.y, WeA[5], mA); mB = f4fma(eb.y, WeB[5], mB);
            mA = f4fma(eb.z, WeA[6], mA); mB = f4fma(eb.z, WeB[6], mB);
            mA = f4fma(eb.w, WeA[7], mA); mB = f4fma(eb.w, WeB[7], mB);
            return f4dot(f4leaky(mA), attA) + f4dot(f4leaky(mB), attB);
        };

        float t0 = logit(x0A, x0B, e0a, e0b);
        float t1 = logit(x1A, x1B, e1a, e1b);
        float t2 = logit(x2A, x2B, e2a, e2b);
        float t3 = logit(x3A, x3B, e3a, e3b);
        #pragma unroll
        for (int off = 8; off; off >>= 1) {
            t0 += __shfl_xor(t0, off, 64);
            t1 += __shfl_xor(t1, off, 64);
            t2 += __shfl_xor(t2, off, 64);
            t3 += __shfl_xor(t3, off, 64);
        }

        if (i + 0 < cnt) {
            float nm = fmaxf(mrun, t0); float sc = __expf(mrun - nm); float p = __expf(t0 - nm);
            den = den * sc + p; accA = f4mix(sc, accA, p, x0A); accB = f4mix(sc, accB, p, x0B); mrun = nm;
        }
        if (i + 1 < cnt) {
            float nm = fmaxf(mrun, t1); float sc = __expf(mrun - nm); float p = __expf(t1 - nm);
            den = den * sc + p; accA = f4mix(sc, accA, p, x1A); accB = f4mix(sc, accB, p, x1B); mrun = nm;
        }
        if (i + 2 < cnt) {
            float nm = fmaxf(mrun, t2); float sc = __expf(mrun - nm); float p = __expf(t2 - nm);
            den = den * sc + p; accA = f4mix(sc, accA, p, x2A); accB = f4mix(sc, accB, p, x2B); mrun = nm;
        }
        if (i + 3 < cnt) {
            float nm = fmaxf(mrun, t3); float sc = __expf(mrun - nm); float p = __expf(t3 - nm);
            den = den * sc + p; accA = f4mix(sc, accA, p, x3A); accB = f4mix(sc, accB, p, x3B); mrun = nm;
        }
    }

    float inv = 1.f / fmaxf(den, 1e-16f);
    float4 oA = make_float4(accA.x * inv + bA.x, accA.y * inv + bA.y,
                            accA.z * inv + bA.z, accA.w * inv + bA.w);
    float4 oB = make_float4(accB.x * inv + bB.x, accB.y * inv + bB.y,
                            accB.z * inv + bB.z, accB.w * inv + bB.w);
    if (RELU) {
        oA = make_float4(fmaxf(oA.x,0.f), fmaxf(oA.y,0.f), fmaxf(oA.z,0.f), fmaxf(oA.w,0.f));
        oB = make_float4(fmaxf(oB.x,0.f), fmaxf(oB.y,0.f), fmaxf(oB.z,0.f), fmaxf(oB.w,0.f));
    }
    float ss = f4dot(oA, oA) + f4dot(oB, oB);
    #pragma unroll
    for (int off = 8; off; off >>= 1) ss += __shfl_xor(ss, off, 64);
    float innv = 1.f / fmaxf(sqrtf(ss), 1e-12f);
    oA = make_float4(oA.x * innv, oA.y * innv, oA.z * innv, oA.w * innv);
    oB = make_float4(oB.x * innv, oB.y * innv, oB.z * innv, oB.w * innv);
    if (has) {
        if (out) {
            float4* op = (float4*)(out + (size_t)d * 128 + c);
            op[0] = oA;
            op[1] = oB;
        }
        if (outb) {
            bf16x8 pk;
            pk[0] = f2bf(oA.x); pk[1] = f2bf(oA.y); pk[2] = f2bf(oA.z); pk[3] = f2bf(oA.w);
            pk[4] = f2bf(oB.x); pk[5] = f2bf(oB.y); pk[6] = f2bf(oB.z); pk[7] = f2bf(oB.w);
            *(bf16x8*)(outb + (size_t)d * 128 + c) = pk;
        }
    }
}

// ---------------- launch ----------------

extern "C" void kernel_launch(void* const* d_in, const int* in_sizes, int n_in,
                              void* d_out, int out_size, void* d_ws, size_t ws_size,
                              hipStream_t stream) {
    const float* x_artist = (const float*)d_in[0];
    const float* x_style  = (const float*)d_in[1];
    const int*   src_aa   = (const int*)d_in[2];
    const int*   dst_aa   = (const int*)d_in[3];
    const float* eattr_aa = (const float*)d_in[4];
    const int*   src_as   = (const int*)d_in[5];
    const int*   dst_as   = (const int*)d_in[6];
    const float* eattr_as = (const float*)d_in[7];
    const float* Wl0_aa = (const float*)d_in[8];
    const float* Wr0_aa = (const float*)d_in[9];
    const float* att0_aa = (const float*)d_in[10];
    const float* We0_aa = (const float*)d_in[11];
    const float* b0_aa = (const float*)d_in[12];
    const float* Wl0_as = (const float*)d_in[13];
    const float* Wr0_as = (const float*)d_in[14];
    const float* att0_as = (const float*)d_in[15];
    const float* We0_as = (const float*)d_in[16];
    const float* b0_as = (const float*)d_in[17];
    const float* Wl_aa = (const float*)d_in[18];
    const float* Wr_aa = (const float*)d_in[19];
    const float* att_aa = (const float*)d_in[20];
    const float* We_aa = (const float*)d_in[21];
    const float* b_aa = (const float*)d_in[22];
    const float* Wl_as = (const float*)d_in[23];
    const float* Wr_as = (const float*)d_in[24];
    const float* att_as = (const float*)d_in[25];
    const float* We_as = (const float*)d_in[26];
    const float* b_as = (const float*)d_in[27];

    float* out = (float*)d_out;

    // ws layout: bf16 regions first, then floats, then ints
    short* Xb    = (short*)d_ws;                    // [NAPAD][128]
    short* Wt    = Xb + (size_t)NAPAD * 128;        // [3][128][128]
    short* bufAb = Wt + 3 * 16384;                  // xl_aa bf16
    short* bufDb = bufAb + (size_t)NA * 128;        // xl_as bf16
    float* fbase = (float*)(bufDb + (size_t)NA * 128);
    size_t off = 0;
    auto allocf = [&](size_t n) { float* r = fbase + off; off += n; return r; };
    float* hS0 = allocf((size_t)NS * CDIM);
    float* hS1 = allocf((size_t)NS * CDIM);
    float* bufB = allocf((size_t)NA * CDIM);   // xr_aa f32
    float* bufC = allocf((size_t)NS * CDIM);   // xr_as f32
    int* ip = (int*)(fbase + off);
    int* rs_aa  = ip;            ip += NA + 1;
    int* cur_aa = ip;            ip += NA;
    int* csr_aa = ip;            ip += E_AA;
    int* rs_as  = ip;            ip += NS + 1;
    int* cur_as = ip;            ip += NS;
    int* csr_as = ip;            ip += E_AS;
    int* perm_aa = ip;           ip += NA;
    int* perm_as = ip;           ip += NS;
    int* dh   = ip;              ip += 256;
    int* dbo  = ip;              ip += 257;
    int* dcur = ip;              ip += 256;

    // ---- CSR + degree-sorted perm, AA ----
    hipMemsetAsync(cur_aa, 0, NA * sizeof(int), stream);
    count_k<<<(E_AA + 255) / 256, 256, 0, stream>>>(dst_aa, E_AA, cur_aa);
    scan_k<<<1, 1024, 0, stream>>>(cur_aa, rs_aa, NA);
    hipMemsetAsync(cur_aa, 0, NA * sizeof(int), stream);
    scatter_k<<<(E_AA + 255) / 256, 256, 0, stream>>>(dst_aa, E_AA, rs_aa, cur_aa, csr_aa);
    hipMemsetAsync(dh, 0, 256 * sizeof(int), stream);
    hipMemsetAsync(dcur, 0, 256 * sizeof(int), stream);
    deghist_k<<<(NA + 255) / 256, 256, 0, stream>>>(rs_aa, NA, dh);
    scan_k<<<1, 1024, 0, stream>>>(dh, dbo, 256);
    degscatter_k<<<(NA + 255) / 256, 256, 0, stream>>>(rs_aa, NA, dbo, dcur, perm_aa);

    // ---- CSR + degree-sorted perm, AS ----
    hipMemsetAsync(cur_as, 0, NS * sizeof(int), stream);
    count_k<<<(E_AS + 255) / 256, 256, 0, stream>>>(dst_as, E_AS, cur_as);
    scan_k<<<1, 1024, 0, stream>>>(cur_as, rs_as, NS);
    hipMemsetAsync(cur_as, 0, NS * sizeof(int), stream);
    scatter_k<<<(E_AS + 255) / 256, 256, 0, stream>>>(dst_as, E_AS, rs_as, cur_as, csr_as);
    hipMemsetAsync(dh, 0, 256 * sizeof(int), stream);
    hipMemsetAsync(dcur, 0, 256 * sizeof(int), stream);
    deghist_k<<<(NS + 255) / 256, 256, 0, stream>>>(rs_as, NS, dh);
    scan_k<<<1, 1024, 0, stream>>>(dh, dbo, 256);
    degscatter_k<<<(NS + 255) / 256, 256, 0, stream>>>(rs_as, NS, dbo, dcur, perm_as);

    // layer-0 X -> bf16
    cvt_k<<<(NA * CDIM / 4 + 255) / 256, 256, 0, stream>>>(x_artist, Xb, NA * CDIM / 4);

    const int gM = NAPAD / 64;
    const int gS = (NS + 31) / 32;
    const int aggA = (NA + 15) / 16;
    const int aggS = (NS + 15) / 16;

    const float* hS_in = x_style;

    for (int layer = 0; layer < 3; ++layer) {
        int j = layer - 1;
        const float *pWl_aa, *pWr_aa, *patt_aa, *pWe_aa, *pb_aa;
        const float *pWl_as, *pWr_as, *patt_as, *pWe_as, *pb_as;
        if (layer == 0) {
            pWl_aa = Wl0_aa; pWr_aa = Wr0_aa; patt_aa = att0_aa; pWe_aa = We0_aa; pb_aa = b0_aa;
            pWl_as = Wl0_as; pWr_as = Wr0_as; patt_as = att0_as; pWe_as = We0_as; pb_as = b0_as;
        } else {
            pWl_aa = Wl_aa + (size_t)j * CDIM * CDIM;
            pWr_aa = Wr_aa + (size_t)j * CDIM * CDIM;
            patt_aa = att_aa + (size_t)j * CDIM;
            pWe_aa = We_aa + (size_t)j * ED * CDIM;
            pb_aa = b_aa + (size_t)j * CDIM;
            pWl_as = Wl_as + (size_t)j * CDIM * CDIM;
            pWr_as = Wr_as + (size_t)j * CDIM * CDIM;
            patt_as = att_as + (size_t)j * CDIM;
            pWe_as = We_as + (size_t)j * ED * CDIM;
            pb_as = b_as + (size_t)j * CDIM;
        }
        // f32 hA output only needed at the final layer
        float* hA_out = (layer == 2) ? out : nullptr;
        float* hS_out = (layer == 2) ? out + (size_t)NA * CDIM : (layer == 0 ? hS0 : hS1);
        short* hA_outb = (layer == 2) ? nullptr : Xb;

        wtr_k<<<3 * 64, 256, 0, stream>>>(pWl_aa, pWr_aa, pWl_as, Wt);

        gemm3_mfma_k<<<gM, 256, 0, stream>>>(Xb, Wt, bufAb, bufB, bufDb, NA);
        if (layer == 0)
            gemm_k<64><<<gS, 256, 0, stream>>>(hS_in, pWr_as, bufC, NS);
        else
            gemm_k<128><<<gS, 256, 0, stream>>>(hS_in, pWr_as, bufC, NS);

        if (layer < 2) {
            agg_k<true><<<aggA, 256, 0, stream>>>(bufAb, bufB, eattr_aa, src_aa, pWe_aa,
                                                  patt_aa, pb_aa, rs_aa, csr_aa, perm_aa,
                                                  hA_out, hA_outb, NA, E_AA);
            agg_k<true><<<aggS, 256, 0, stream>>>(bufDb, bufC, eattr_as, src_as, pWe_as,
                                                  patt_as, pb_as, rs_as, csr_as, perm_as,
                                                  hS_out, nullptr, NS, E_AS);
        } else {
            agg_k<false><<<aggA, 256, 0, stream>>>(bufAb, bufB, eattr_aa, src_aa, pWe_aa,
                                                   patt_aa, pb_aa, rs_aa, csr_aa, perm_aa,
                                                   hA_out, nullptr, NA, E_AA);
            agg_k<false><<<aggS, 256, 0, stream>>>(bufDb, bufC, eattr_as, src_as, pWe_as,
                                                   patt_as, pb_as, rs_as, csr_as, perm_as,
                                                   hS_out, nullptr, NS, E_AS);
        }

        hS_in = hS_out;
    }
}

// Round 8
// 691.996 us; speedup vs baseline: 3.3805x; 1.3212x over previous
//
#include <hip/hip_runtime.h>
#include <hip/hip_bf16.h>
#include <math.h>

#define NA 50000
#define NS 5000
#define E_AA 500000
#define E_AS 250000
#define CDIM 128
#define ED 8
#define NAPAD 50048   // 782*64
#define NSPAD 5056    // 79*64
#define SCAN_CH 2048  // elements per scan block (256 thr x 8)

typedef __attribute__((ext_vector_type(8))) short bf16x8;
typedef __attribute__((ext_vector_type(4))) float f32x4;

__device__ inline short f2bf(float f) {
    __hip_bfloat16 h = __float2bfloat16(f);
    return *(short*)&h;
}
__device__ inline float bf2f(short s) {
    union { unsigned int u; float f; } cv;
    cv.u = ((unsigned int)(unsigned short)s) << 16;
    return cv.f;
}

// ---------------- small helpers ----------------

__device__ inline float4 f4fma(float s, float4 a, float4 b) {
    return make_float4(fmaf(s, a.x, b.x), fmaf(s, a.y, b.y),
                       fmaf(s, a.z, b.z), fmaf(s, a.w, b.w));
}
__device__ inline float4 f4add(float4 a, float4 b) {
    return make_float4(a.x + b.x, a.y + b.y, a.z + b.z, a.w + b.w);
}
__device__ inline float4 f4leaky(float4 a) {
    return make_float4(a.x > 0.f ? a.x : 0.2f * a.x, a.y > 0.f ? a.y : 0.2f * a.y,
                       a.z > 0.f ? a.z : 0.2f * a.z, a.w > 0.f ? a.w : 0.2f * a.w);
}
__device__ inline float f4dot(float4 a, float4 b) {
    return a.x * b.x + a.y * b.y + a.z * b.z + a.w * b.w;
}
__device__ inline float4 f4mix(float sc, float4 a, float p, float4 x) {
    return make_float4(fmaf(sc, a.x, p * x.x), fmaf(sc, a.y, p * x.y),
                       fmaf(sc, a.z, p * x.z), fmaf(sc, a.w, p * x.w));
}

// ---------------- CSR build (both edge types per dispatch) ----------------

__global__ __launch_bounds__(256) void count2_k(const int* __restrict__ dst0,
                                                const int* __restrict__ dst1,
                                                int* __restrict__ deg0,
                                                int* __restrict__ deg1) {
    int e = blockIdx.x * 256 + threadIdx.x;
    if (e < E_AA) atomicAdd(&deg0[dst0[e]], 1);
    if (e < E_AS) atomicAdd(&deg1[dst1[e]], 1);
}

// phase A: per-block sums of deg (two concatenated arrays)
__global__ __launch_bounds__(256) void scanA_k(const int* __restrict__ deg0, int n0,
                                               const int* __restrict__ deg1, int n1,
                                               int nb0, int* __restrict__ bsum) {
    int b = blockIdx.x;
    const int* deg; int n; int lb;
    if ((int)b < nb0) { deg = deg0; n = n0; lb = b; }
    else { deg = deg1; n = n1; lb = b - nb0; }
    int t = threadIdx.x;
    int base = lb * SCAN_CH + t * 8;
    int s = 0;
    #pragma unroll
    for (int i = 0; i < 8; ++i) { int idx = base + i; s += (idx < n) ? deg[idx] : 0; }
    int lane = t & 63, w = t >> 6;
    #pragma unroll
    for (int off = 1; off < 64; off <<= 1) {
        int u = __shfl_up(s, off, 64);
        if (lane >= off) s += u;
    }
    __shared__ int ws[4];
    if (lane == 63) ws[w] = s;
    __syncthreads();
    if (t == 0) {
        int tot = ws[0] + ws[1] + ws[2] + ws[3];
        bsum[blockIdx.x] = tot;
    }
}

// phase B: exclusive-scan the 28 block sums (two segments) in one wave
__global__ void scanB_k(int* __restrict__ bsum, int nb0, int nb1) {
    int t = threadIdx.x;   // 64
    int n = nb0 + nb1;
    int v = (t < n) ? bsum[t] : 0;
    int incl = v;
    #pragma unroll
    for (int off = 1; off < 64; off <<= 1) {
        int u = __shfl_up(incl, off, 64);
        if (t >= off) incl += u;
    }
    int excl = incl - v;
    int sum0 = __shfl(incl, nb0 - 1, 64);
    if (t >= nb0) excl -= sum0;
    if (t < n) bsum[t] = excl;
}

// phase C: block-local prefix + global offset -> row_start (exclusive), plus rs[n]
__global__ __launch_bounds__(256) void scanC_k(const int* __restrict__ deg0, int n0,
                                               const int* __restrict__ deg1, int n1,
                                               int nb0, const int* __restrict__ bsum,
                                               int* __restrict__ rs0, int* __restrict__ rs1) {
    int b = blockIdx.x;
    const int* deg; int n; int* rs; int lb;
    if ((int)b < nb0) { deg = deg0; n = n0; rs = rs0; lb = b; }
    else { deg = deg1; n = n1; rs = rs1; lb = b - nb0; }
    int boff = bsum[b];
    int t = threadIdx.x;
    int base = lb * SCAN_CH + t * 8;
    int v[8];
    int tsum = 0;
    #pragma unroll
    for (int i = 0; i < 8; ++i) {
        int idx = base + i;
        v[i] = (idx < n) ? deg[idx] : 0;
        tsum += v[i];
    }
    int lane = t & 63, w = t >> 6;
    int incl = tsum;
    #pragma unroll
    for (int off = 1; off < 64; off <<= 1) {
        int u = __shfl_up(incl, off, 64);
        if (lane >= off) incl += u;
    }
    __shared__ int ws[4];
    if (lane == 63) ws[w] = incl;
    __syncthreads();
    int woff = 0;
    for (int i = 0; i < w; ++i) woff += ws[i];
    int run = boff + woff + incl - tsum;
    #pragma unroll
    for (int i = 0; i < 8; ++i) {
        int idx = base + i;
        if (idx < n) {
            rs[idx] = run;
            run += v[i];
            if (idx == n - 1) rs[n] = run;
        }
    }
}

__global__ __launch_bounds__(256) void scatter2_k(const int* __restrict__ dst0,
                                                  const int* __restrict__ dst1,
                                                  const int* __restrict__ rs0,
                                                  const int* __restrict__ rs1,
                                                  int* __restrict__ cur0,
                                                  int* __restrict__ cur1,
                                                  int* __restrict__ csr0,
                                                  int* __restrict__ csr1) {
    int e = blockIdx.x * 256 + threadIdx.x;
    if (e < E_AA) {
        int d = dst0[e];
        int pos = atomicAdd(&cur0[d], 1);
        csr0[rs0[d] + pos] = e;
    }
    if (e < E_AS) {
        int d = dst1[e];
        int pos = atomicAdd(&cur1[d], 1);
        csr1[rs1[d] + pos] = e;
    }
}

// ---- degree counting-sort (LDS hist, both node types per dispatch) ----

__global__ __launch_bounds__(256) void deghist2_k(const int* __restrict__ rs0, int n0,
                                                  const int* __restrict__ rs1, int n1,
                                                  int nb0, int* __restrict__ dh0,
                                                  int* __restrict__ dh1) {
    int b = blockIdx.x;
    const int* rs; int n; int* dh; int lb;
    if ((int)b < nb0) { rs = rs0; n = n0; dh = dh0; lb = b; }
    else { rs = rs1; n = n1; dh = dh1; lb = b - nb0; }
    __shared__ int lh[256];
    int t = threadIdx.x;
    lh[t] = 0;
    __syncthreads();
    int d = lb * 256 + t;
    if (d < n) {
        int deg = rs[d + 1] - rs[d];
        if (deg > 255) deg = 255;
        atomicAdd(&lh[deg], 1);
    }
    __syncthreads();
    if (lh[t]) atomicAdd(&dh[t], lh[t]);
}

// exclusive scan of the two 256-bin histograms: wave0 -> dh0, wave1 -> dh1
__global__ void binscan2_k(const int* __restrict__ dh0, const int* __restrict__ dh1,
                           int* __restrict__ dbo0, int* __restrict__ dbo1) {
    int w = threadIdx.x >> 6, lane = threadIdx.x & 63;
    const int* dh = w ? dh1 : dh0;
    int* dbo = w ? dbo1 : dbo0;
    int v[4]; int s = 0;
    #pragma unroll
    for (int i = 0; i < 4; ++i) { v[i] = dh[lane * 4 + i]; s += v[i]; }
    int incl = s;
    #pragma unroll
    for (int off = 1; off < 64; off <<= 1) {
        int u = __shfl_up(incl, off, 64);
        if (lane >= off) incl += u;
    }
    int run = incl - s;
    #pragma unroll
    for (int i = 0; i < 4; ++i) { dbo[lane * 4 + i] = run; run += v[i]; }
}

__global__ __launch_bounds__(256) void degscatter2_k(const int* __restrict__ rs0, int n0,
                                                     const int* __restrict__ rs1, int n1,
                                                     int nb0,
                                                     const int* __restrict__ dbo0,
                                                     const int* __restrict__ dbo1,
                                                     int* __restrict__ dcur0,
                                                     int* __restrict__ dcur1,
                                                     int* __restrict__ perm0,
                                                     int* __restrict__ perm1) {
    int b = blockIdx.x;
    const int* rs; int n; const int* dbo; int* dcur; int* perm; int lb;
    if ((int)b < nb0) { rs = rs0; n = n0; dbo = dbo0; dcur = dcur0; perm = perm0; lb = b; }
    else { rs = rs1; n = n1; dbo = dbo1; dcur = dcur1; perm = perm1; lb = b - nb0; }
    __shared__ int lh[256];
    __shared__ int lbase[256];
    int t = threadIdx.x;
    lh[t] = 0;
    __syncthreads();
    int d = lb * 256 + t;
    int deg = 0, lpos = 0;
    if (d < n) {
        deg = rs[d + 1] - rs[d];
        if (deg > 255) deg = 255;
        lpos = atomicAdd(&lh[deg], 1);
    }
    __syncthreads();
    int cnt = lh[t];
    if (cnt) lbase[t] = atomicAdd(&dcur[t], cnt);
    __syncthreads();
    if (d < n) perm[dbo[deg] + lbase[deg] + lpos] = d;
}

// ---------------- converts: x_artist -> Xb, x_style -> Xsb (zero-padded) ----------------

__global__ __launch_bounds__(256) void cvt2_k(const float* __restrict__ xa,
                                              const float* __restrict__ xs,
                                              short* __restrict__ Xb,
                                              short* __restrict__ Xsb) {
    const int t4A = NAPAD * 32;
    const int t4S = NSPAD * 32;
    int i = blockIdx.x * 256 + threadIdx.x;
    if (i < t4A) {
        int row = i >> 5, c4 = i & 31;
        float4 v = make_float4(0.f, 0.f, 0.f, 0.f);
        if (row < NA) v = ((const float4*)xa)[(size_t)row * 32 + c4];
        short4 s;
        s.x = f2bf(v.x); s.y = f2bf(v.y); s.z = f2bf(v.z); s.w = f2bf(v.w);
        ((short4*)Xb)[i] = s;
    } else if (i < t4A + t4S) {
        int j = i - t4A;
        int row = j >> 5, c4 = j & 31;
        float4 v = make_float4(0.f, 0.f, 0.f, 0.f);
        if (row < NS && c4 < 16) v = ((const float4*)xs)[(size_t)row * 16 + c4];  // DIN_S=64
        short4 s;
        s.x = f2bf(v.x); s.y = f2bf(v.y); s.z = f2bf(v.z); s.w = f2bf(v.w);
        ((short4*)Xsb)[j] = s;
    }
}

// ---------------- all 12 weight transposes upfront: Wt[layer][w][n][k] bf16 ----------------
// w: 0=Wl_aa 1=Wr_aa 2=Wl_as 3=Wr_as (layer0 Wr_as is 64x128 -> zero-pad k>=64)

__global__ __launch_bounds__(256) void wtr12_k(
    const float* __restrict__ Wl0_aa, const float* __restrict__ Wr0_aa,
    const float* __restrict__ Wl0_as, const float* __restrict__ Wr0_as,
    const float* __restrict__ Wl_aa, const float* __restrict__ Wr_aa,
    const float* __restrict__ Wl_as, const float* __restrict__ Wr_as,
    short* __restrict__ Wt) {
    int mat = blockIdx.x >> 6;            // 0..11
    int layer = mat >> 2, w = mat & 3;
    int idx = (blockIdx.x & 63) * 256 + threadIdx.x;  // 0..16383, = k*128+n
    int k = idx >> 7, n = idx & 127;
    const float* W;
    int K = 128;
    if (layer == 0) {
        W = (w == 0) ? Wl0_aa : (w == 1) ? Wr0_aa : (w == 2) ? Wl0_as : Wr0_as;
        if (w == 3) K = 64;
    } else {
        int j = layer - 1;
        W = ((w == 0) ? Wl_aa : (w == 1) ? Wr_aa : (w == 2) ? Wl_as : Wr_as)
            + (size_t)j * 16384;
    }
    float v = (k < K) ? W[(size_t)k * 128 + n] : 0.f;
    Wt[(size_t)mat * 16384 + n * 128 + k] = f2bf(v);
}

// ---------------- MFMA quad GEMM: artist (3 outputs) + style (1 output) ----------------

__global__ __launch_bounds__(256) void gemm4_k(
    const short* __restrict__ Xb, const short* __restrict__ Xsb,
    const short* __restrict__ Wt,
    short* __restrict__ Y0b, float* __restrict__ Y1, short* __restrict__ Y2b,
    float* __restrict__ Y3, int gM) {
    int t = threadIdx.x;
    int wave = t >> 6, lane = t & 63;
    int quad = lane >> 4, l16 = lane & 15;
    bool style = (int)blockIdx.x >= gM;
    int rblk = style ? (int)blockIdx.x - gM : (int)blockIdx.x;
    const short* X = style ? Xsb : Xb;
    int rbase = rblk * 64 + wave * 16;

    bf16x8 a[4];
    const short* arow = X + (size_t)(rbase + l16) * 128 + quad * 8;
    #pragma unroll
    for (int kb = 0; kb < 4; ++kb) a[kb] = *(const bf16x8*)(arow + kb * 32);

    if (!style) {
        #pragma unroll
        for (int w = 0; w < 3; ++w) {
            const short* Wb = Wt + (size_t)w * 16384;
            #pragma unroll
            for (int nt = 0; nt < 8; ++nt) {
                f32x4 acc = {0.f, 0.f, 0.f, 0.f};
                const short* brow = Wb + (size_t)(nt * 16 + l16) * 128 + quad * 8;
                #pragma unroll
                for (int kb = 0; kb < 4; ++kb) {
                    bf16x8 b = *(const bf16x8*)(brow + kb * 32);
                    acc = __builtin_amdgcn_mfma_f32_16x16x32_bf16(a[kb], b, acc, 0, 0, 0);
                }
                int col = nt * 16 + l16;
                #pragma unroll
                for (int r = 0; r < 4; ++r) {
                    int row = rbase + quad * 4 + r;
                    if (row < NA) {
                        if (w == 1) Y1[(size_t)row * 128 + col] = acc[r];
                        else if (w == 0) Y0b[(size_t)row * 128 + col] = f2bf(acc[r]);
                        else Y2b[(size_t)row * 128 + col] = f2bf(acc[r]);
                    }
                }
            }
        }
    } else {
        const short* Wb = Wt + (size_t)3 * 16384;
        #pragma unroll
        for (int nt = 0; nt < 8; ++nt) {
            f32x4 acc = {0.f, 0.f, 0.f, 0.f};
            const short* brow = Wb + (size_t)(nt * 16 + l16) * 128 + quad * 8;
            #pragma unroll
            for (int kb = 0; kb < 4; ++kb) {
                bf16x8 b = *(const bf16x8*)(brow + kb * 32);
                acc = __builtin_amdgcn_mfma_f32_16x16x32_bf16(a[kb], b, acc, 0, 0, 0);
            }
            int col = nt * 16 + l16;
            #pragma unroll
            for (int r = 0; r < 4; ++r) {
                int row = rbase + quad * 4 + r;
                if (row < NS) Y3[(size_t)row * 128 + col] = acc[r];
            }
        }
    }
}

// ---------------- fused GATv2 aggregation, AA + AS in one dispatch ----------------
// 4 dst/wave, 16 lanes/dst; xl gathered bf16. launch_bounds (256,2): (256,4)
// forces a 128-VGPR cap -> spill -> 1.5 GB scratch traffic (R6 regression).

template<bool RELU>
__global__ __launch_bounds__(256, 2) void agg2_k(
    const short* __restrict__ xl0, const float* __restrict__ xr0,
    const float* __restrict__ ea0, const int* __restrict__ src0,
    const float* __restrict__ We0, const float* __restrict__ att0,
    const float* __restrict__ bias0, const int* __restrict__ rs0,
    const int* __restrict__ csr0, const int* __restrict__ perm0,
    float* __restrict__ out0, short* __restrict__ outb0, int nd0, int E0, int nblk0,
    const short* __restrict__ xl1, const float* __restrict__ xr1,
    const float* __restrict__ ea1, const int* __restrict__ src1,
    const float* __restrict__ We1, const float* __restrict__ att1,
    const float* __restrict__ bias1, const int* __restrict__ rs1,
    const int* __restrict__ csr1, const int* __restrict__ perm1,
    float* __restrict__ out1, short* __restrict__ outb1, int nd1, int E1) {

    const short* xl; const float* xr_; const float* eattr; const int* srcv;
    const float* We; const float* att; const float* bias;
    const int* row_start; const int* csr_eid; const int* perm;
    float* out; short* outb; int ndst, Etot, blk;
    if ((int)blockIdx.x < nblk0) {
        xl = xl0; xr_ = xr0; eattr = ea0; srcv = src0; We = We0; att = att0; bias = bias0;
        row_start = rs0; csr_eid = csr0; perm = perm0; out = out0; outb = outb0;
        ndst = nd0; Etot = E0; blk = blockIdx.x;
    } else {
        xl = xl1; xr_ = xr1; eattr = ea1; srcv = src1; We = We1; att = att1; bias = bias1;
        row_start = rs1; csr_eid = csr1; perm = perm1; out = out1; outb = outb1;
        ndst = nd1; Etot = E1; blk = blockIdx.x - nblk0;
    }

    int wave = threadIdx.x >> 6;
    int lane = threadIdx.x & 63;
    int g = lane >> 4;
    int sl = lane & 15;
    int c = sl * 8;

    int di = blk * 16 + wave * 4 + g;
    bool has = di < ndst;
    int d = has ? perm[di] : 0;

    float4 WeA[8], WeB[8];
    #pragma unroll
    for (int k = 0; k < 8; ++k) {
        WeA[k] = *(const float4*)(We + k * 128 + c);
        WeB[k] = *(const float4*)(We + k * 128 + c + 4);
    }
    float4 attA = *(const float4*)(att + c);
    float4 attB = *(const float4*)(att + c + 4);
    float4 bA = *(const float4*)(bias + c);
    float4 bB = *(const float4*)(bias + c + 4);
    float4 xrA = *(const float4*)(xr_ + (size_t)d * 128 + c);
    float4 xrB = *(const float4*)(xr_ + (size_t)d * 128 + c + 4);

    float4 accA = {0,0,0,0}, accB = {0,0,0,0};
    float den = 0.f, mrun = -INFINITY;

    int e0 = has ? row_start[d] : 0;
    int cnt = has ? row_start[d + 1] - e0 : 0;

    for (int i = 0; ; i += 4) {
        if (!__any(i < cnt)) break;

        int idx0 = e0 + i;
        int c0 = idx0 < Etot ? idx0 : Etot - 1;
        int c1 = idx0 + 1 < Etot ? idx0 + 1 : Etot - 1;
        int c2 = idx0 + 2 < Etot ? idx0 + 2 : Etot - 1;
        int c3 = idx0 + 3 < Etot ? idx0 + 3 : Etot - 1;
        int ei0 = csr_eid[c0], ei1 = csr_eid[c1], ei2 = csr_eid[c2], ei3 = csr_eid[c3];
        int s0 = srcv[ei0], s1 = srcv[ei1], s2 = srcv[ei2], s3 = srcv[ei3];

        bf16x8 xb0 = *(const bf16x8*)(xl + (size_t)s0 * 128 + c);
        bf16x8 xb1 = *(const bf16x8*)(xl + (size_t)s1 * 128 + c);
        bf16x8 xb2 = *(const bf16x8*)(xl + (size_t)s2 * 128 + c);
        bf16x8 xb3 = *(const bf16x8*)(xl + (size_t)s3 * 128 + c);
        const float4* q0 = (const float4*)(eattr + (size_t)ei0 * 8);
        const float4* q1 = (const float4*)(eattr + (size_t)ei1 * 8);
        const float4* q2 = (const float4*)(eattr + (size_t)ei2 * 8);
        const float4* q3 = (const float4*)(eattr + (size_t)ei3 * 8);
        float4 e0a = q0[0], e0b = q0[1];
        float4 e1a = q1[0], e1b = q1[1];
        float4 e2a = q2[0], e2b = q2[1];
        float4 e3a = q3[0], e3b = q3[1];

        float4 x0A = make_float4(bf2f(xb0[0]), bf2f(xb0[1]), bf2f(xb0[2]), bf2f(xb0[3]));
        float4 x0B = make_float4(bf2f(xb0[4]), bf2f(xb0[5]), bf2f(xb0[6]), bf2f(xb0[7]));
        float4 x1A = make_float4(bf2f(xb1[0]), bf2f(xb1[1]), bf2f(xb1[2]), bf2f(xb1[3]));
        float4 x1B = make_float4(bf2f(xb1[4]), bf2f(xb1[5]), bf2f(xb1[6]), bf2f(xb1[7]));
        float4 x2A = make_float4(bf2f(xb2[0]), bf2f(xb2[1]), bf2f(xb2[2]), bf2f(xb2[3]));
        float4 x2B = make_float4(bf2f(xb2[4]), bf2f(xb2[5]), bf2f(xb2[6]), bf2f(xb2[7]));
        float4 x3A = make_float4(bf2f(xb3[0]), bf2f(xb3[1]), bf2f(xb3[2]), bf2f(xb3[3]));
        float4 x3B = make_float4(bf2f(xb3[4]), bf2f(xb3[5]), bf2f(xb3[6]), bf2f(xb3[7]));

        auto logit = [&](float4 xA, float4 xB, float4 ea, float4 eb) -> float {
            float4 mA = f4add(xA, xrA), mB = f4add(xB, xrB);
            mA = f4fma(ea.x, WeA[0], mA); mB = f4fma(ea.x, WeB[0], mB);
            mA = f4fma(ea.y, WeA[1], mA); mB = f4fma(ea.y, WeB[1], mB);
            mA = f4fma(ea.z, WeA[2], mA); mB = f4fma(ea.z, WeB[2], mB);
            mA = f4fma(ea.w, WeA[3], mA); mB = f4fma(ea.w, WeB[3], mB);
            mA = f4fma(eb.x, WeA[4], mA); mB = f4fma(eb.x, WeB[4], mB);
            mA = f4fma(eb.y, WeA[5], mA); mB = f4fma(eb.y, WeB[5], mB);
            mA = f4fma(eb.z, WeA[6], mA); mB = f4fma(eb.z, WeB[6], mB);
            mA = f4fma(eb.w, WeA[7], mA); mB = f4fma(eb.w, WeB[7], mB);
            return f4dot(f4leaky(mA), attA) + f4dot(f4leaky(mB), attB);
        };

        float t0 = logit(x0A, x0B, e0a, e0b);
        float t1 = logit(x1A, x1B, e1a, e1b);
        float t2 = logit(x2A, x2B, e2a, e2b);
        float t3 = logit(x3A, x3B, e3a, e3b);
        #pragma unroll
        for (int off = 8; off; off >>= 1) {
            t0 += __shfl_xor(t0, off, 64);
            t1 += __shfl_xor(t1, off, 64);
            t2 += __shfl_xor(t2, off, 64);
            t3 += __shfl_xor(t3, off, 64);
        }

        if (i + 0 < cnt) {
            float nm = fmaxf(mrun, t0); float sc = __expf(mrun - nm); float p = __expf(t0 - nm);
            den = den * sc + p; accA = f4mix(sc, accA, p, x0A); accB = f4mix(sc, accB, p, x0B); mrun = nm;
        }
        if (i + 1 < cnt) {
            float nm = fmaxf(mrun, t1); float sc = __expf(mrun - nm); float p = __expf(t1 - nm);
            den = den * sc + p; accA = f4mix(sc, accA, p, x1A); accB = f4mix(sc, accB, p, x1B); mrun = nm;
        }
        if (i + 2 < cnt) {
            float nm = fmaxf(mrun, t2); float sc = __expf(mrun - nm); float p = __expf(t2 - nm);
            den = den * sc + p; accA = f4mix(sc, accA, p, x2A); accB = f4mix(sc, accB, p, x2B); mrun = nm;
        }
        if (i + 3 < cnt) {
            float nm = fmaxf(mrun, t3); float sc = __expf(mrun - nm); float p = __expf(t3 - nm);
            den = den * sc + p; accA = f4mix(sc, accA, p, x3A); accB = f4mix(sc, accB, p, x3B); mrun = nm;
        }
    }

    float inv = 1.f / fmaxf(den, 1e-16f);
    float4 oA = make_float4(accA.x * inv + bA.x, accA.y * inv + bA.y,
                            accA.z * inv + bA.z, accA.w * inv + bA.w);
    float4 oB = make_float4(accB.x * inv + bB.x, accB.y * inv + bB.y,
                            accB.z * inv + bB.z, accB.w * inv + bB.w);
    if (RELU) {
        oA = make_float4(fmaxf(oA.x,0.f), fmaxf(oA.y,0.f), fmaxf(oA.z,0.f), fmaxf(oA.w,0.f));
        oB = make_float4(fmaxf(oB.x,0.f), fmaxf(oB.y,0.f), fmaxf(oB.z,0.f), fmaxf(oB.w,0.f));
    }
    float ss = f4dot(oA, oA) + f4dot(oB, oB);
    #pragma unroll
    for (int off = 8; off; off >>= 1) ss += __shfl_xor(ss, off, 64);
    float innv = 1.f / fmaxf(sqrtf(ss), 1e-12f);
    oA = make_float4(oA.x * innv, oA.y * innv, oA.z * innv, oA.w * innv);
    oB = make_float4(oB.x * innv, oB.y * innv, oB.z * innv, oB.w * innv);
    if (has) {
        if (out) {
            float4* op = (float4*)(out + (size_t)d * 128 + c);
            op[0] = oA;
            op[1] = oB;
        }
        if (outb) {
            bf16x8 pk;
            pk[0] = f2bf(oA.x); pk[1] = f2bf(oA.y); pk[2] = f2bf(oA.z); pk[3] = f2bf(oA.w);
            pk[4] = f2bf(oB.x); pk[5] = f2bf(oB.y); pk[6] = f2bf(oB.z); pk[7] = f2bf(oB.w);
            *(bf16x8*)(outb + (size_t)d * 128 + c) = pk;
        }
    }
}

// ---------------- launch ----------------

extern "C" void kernel_launch(void* const* d_in, const int* in_sizes, int n_in,
                              void* d_out, int out_size, void* d_ws, size_t ws_size,
                              hipStream_t stream) {
    const float* x_artist = (const float*)d_in[0];
    const float* x_style  = (const float*)d_in[1];
    const int*   src_aa   = (const int*)d_in[2];
    const int*   dst_aa   = (const int*)d_in[3];
    const float* eattr_aa = (const float*)d_in[4];
    const int*   src_as   = (const int*)d_in[5];
    const int*   dst_as   = (const int*)d_in[6];
    const float* eattr_as = (const float*)d_in[7];
    const float* Wl0_aa = (const float*)d_in[8];
    const float* Wr0_aa = (const float*)d_in[9];
    const float* att0_aa = (const float*)d_in[10];
    const float* We0_aa = (const float*)d_in[11];
    const float* b0_aa = (const float*)d_in[12];
    const float* Wl0_as = (const float*)d_in[13];
    const float* Wr0_as = (const float*)d_in[14];
    const float* att0_as = (const float*)d_in[15];
    const float* We0_as = (const float*)d_in[16];
    const float* b0_as = (const float*)d_in[17];
    const float* Wl_aa = (const float*)d_in[18];
    const float* Wr_aa = (const float*)d_in[19];
    const float* att_aa = (const float*)d_in[20];
    const float* We_aa = (const float*)d_in[21];
    const float* b_aa = (const float*)d_in[22];
    const float* Wl_as = (const float*)d_in[23];
    const float* Wr_as = (const float*)d_in[24];
    const float* att_as = (const float*)d_in[25];
    const float* We_as = (const float*)d_in[26];
    const float* b_as = (const float*)d_in[27];

    float* out = (float*)d_out;

    // ws layout: bf16 regions, f32 regions, int regions
    short* Xb    = (short*)d_ws;                       // [NAPAD][128]
    short* Xsb   = Xb + (size_t)NAPAD * 128;           // [NSPAD][128]
    short* Wt    = Xsb + (size_t)NSPAD * 128;          // [3][4][128][128]
    short* bufAb = Wt + 12 * 16384;                    // xl_aa bf16
    short* bufDb = bufAb + (size_t)NA * 128;           // xl_as bf16
    float* fbase = (float*)(bufDb + (size_t)NA * 128);
    size_t off = 0;
    auto allocf = [&](size_t n) { float* r = fbase + off; off += n; return r; };
    float* bufB = allocf((size_t)NA * CDIM);   // xr_aa f32
    float* bufC = allocf((size_t)NSPAD * CDIM); // xr_as f32
    int* ip = (int*)(fbase + off);
    // zeroed zone (single memset): deg_aa, cur_aa, deg_as, cur_as, dh(512), dcur(512)
    int* zbase  = ip;
    int* deg_aa = ip;            ip += NA;
    int* cur_aa = ip;            ip += NA;
    int* deg_as = ip;            ip += NS;
    int* cur_as = ip;            ip += NS;
    int* dh_aa  = ip;            ip += 256;
    int* dh_as  = ip;            ip += 256;
    int* dcur_aa = ip;           ip += 256;
    int* dcur_as = ip;           ip += 256;
    size_t zbytes = (size_t)(ip - zbase) * sizeof(int);
    // non-zeroed
    int* rs_aa  = ip;            ip += NA + 1;
    int* rs_as  = ip;            ip += NS + 1;
    int* csr_aa = ip;            ip += E_AA;
    int* csr_as = ip;            ip += E_AS;
    int* perm_aa = ip;           ip += NA;
    int* perm_as = ip;           ip += NS;
    int* dbo_aa = ip;            ip += 256;
    int* dbo_as = ip;            ip += 256;
    int* bsum   = ip;            ip += 64;

    const int nbA_scan = (NA + SCAN_CH - 1) / SCAN_CH;   // 25
    const int nbS_scan = (NS + SCAN_CH - 1) / SCAN_CH;   // 3
    const int nbA_node = (NA + 255) / 256;               // 196
    const int nbS_node = (NS + 255) / 256;               // 20
    const int gE = (E_AA + 255) / 256;

    // ---- preprocessing (one pass, both edge types) ----
    hipMemsetAsync(zbase, 0, zbytes, stream);
    count2_k<<<gE, 256, 0, stream>>>(dst_aa, dst_as, deg_aa, deg_as);
    scanA_k<<<nbA_scan + nbS_scan, 256, 0, stream>>>(deg_aa, NA, deg_as, NS, nbA_scan, bsum);
    scanB_k<<<1, 64, 0, stream>>>(bsum, nbA_scan, nbS_scan);
    scanC_k<<<nbA_scan + nbS_scan, 256, 0, stream>>>(deg_aa, NA, deg_as, NS, nbA_scan,
                                                     bsum, rs_aa, rs_as);
    scatter2_k<<<gE, 256, 0, stream>>>(dst_aa, dst_as, rs_aa, rs_as,
                                       cur_aa, cur_as, csr_aa, csr_as);
    deghist2_k<<<nbA_node + nbS_node, 256, 0, stream>>>(rs_aa, NA, rs_as, NS, nbA_node,
                                                        dh_aa, dh_as);
    binscan2_k<<<1, 128, 0, stream>>>(dh_aa, dh_as, dbo_aa, dbo_as);
    degscatter2_k<<<nbA_node + nbS_node, 256, 0, stream>>>(rs_aa, NA, rs_as, NS, nbA_node,
                                                           dbo_aa, dbo_as, dcur_aa, dcur_as,
                                                           perm_aa, perm_as);
    cvt2_k<<<(NAPAD * 32 + NSPAD * 32 + 255) / 256, 256, 0, stream>>>(x_artist, x_style,
                                                                      Xb, Xsb);
    wtr12_k<<<12 * 64, 256, 0, stream>>>(Wl0_aa, Wr0_aa, Wl0_as, Wr0_as,
                                         Wl_aa, Wr_aa, Wl_as, Wr_as, Wt);

    const int gM = NAPAD / 64;      // 782
    const int gS4 = NSPAD / 64;     // 79
    const int aggA = (NA + 15) / 16;  // 3125
    const int aggS = (NS + 15) / 16;  // 313

    for (int layer = 0; layer < 3; ++layer) {
        int j = layer - 1;
        const float *patt_aa, *pWe_aa, *pb_aa, *patt_as, *pWe_as, *pb_as;
        if (layer == 0) {
            patt_aa = att0_aa; pWe_aa = We0_aa; pb_aa = b0_aa;
            patt_as = att0_as; pWe_as = We0_as; pb_as = b0_as;
        } else {
            patt_aa = att_aa + (size_t)j * CDIM;
            pWe_aa = We_aa + (size_t)j * ED * CDIM;
            pb_aa = b_aa + (size_t)j * CDIM;
            patt_as = att_as + (size_t)j * CDIM;
            pWe_as = We_as + (size_t)j * ED * CDIM;
            pb_as = b_as + (size_t)j * CDIM;
        }
        const short* pWt = Wt + (size_t)layer * 4 * 16384;
        float* hA_out = (layer == 2) ? out : nullptr;
        float* hS_out = (layer == 2) ? out + (size_t)NA * CDIM : nullptr;
        short* hA_outb = (layer == 2) ? nullptr : Xb;
        short* hS_outb = (layer == 2) ? nullptr : Xsb;

        gemm4_k<<<gM + gS4, 256, 0, stream>>>(Xb, Xsb, pWt, bufAb, bufB, bufDb, bufC, gM);

        if (layer < 2)
            agg2_k<true><<<aggA + aggS, 256, 0, stream>>>(
                bufAb, bufB, eattr_aa, src_aa, pWe_aa, patt_aa, pb_aa,
                rs_aa, csr_aa, perm_aa, hA_out, hA_outb, NA, E_AA, aggA,
                bufDb, bufC, eattr_as, src_as, pWe_as, patt_as, pb_as,
                rs_as, csr_as, perm_as, hS_out, hS_outb, NS, E_AS);
        else
            agg2_k<false><<<aggA + aggS, 256, 0, stream>>>(
                bufAb, bufB, eattr_aa, src_aa, pWe_aa, patt_aa, pb_aa,
                rs_aa, csr_aa, perm_aa, hA_out, hA_outb, NA, E_AA, aggA,
                bufDb, bufC, eattr_as, src_as, pWe_as, patt_as, pb_as,
                rs_as, csr_as, perm_as, hS_out, hS_outb, NS, E_AS);
    }
}

// Round 9
// 679.826 us; speedup vs baseline: 3.4411x; 1.0179x over previous
//
#include <hip/hip_runtime.h>
#include <hip/hip_bf16.h>
#include <math.h>

#define NA 50000
#define NS 5000
#define E_AA 500000
#define E_AS 250000
#define CDIM 128
#define ED 8
#define NAPAD 50048   // 782*64
#define NSPAD 5056    // 79*64
#define SCAN_CH 2048  // elements per scan block (256 thr x 8)

typedef __attribute__((ext_vector_type(8))) short bf16x8;
typedef __attribute__((ext_vector_type(4))) float f32x4;

__device__ inline short f2bf(float f) {
    __hip_bfloat16 h = __float2bfloat16(f);
    return *(short*)&h;
}
__device__ inline float bf2f(short s) {
    union { unsigned int u; float f; } cv;
    cv.u = ((unsigned int)(unsigned short)s) << 16;
    return cv.f;
}

// ---------------- small helpers ----------------

__device__ inline float4 f4fma(float s, float4 a, float4 b) {
    return make_float4(fmaf(s, a.x, b.x), fmaf(s, a.y, b.y),
                       fmaf(s, a.z, b.z), fmaf(s, a.w, b.w));
}
__device__ inline float4 f4add(float4 a, float4 b) {
    return make_float4(a.x + b.x, a.y + b.y, a.z + b.z, a.w + b.w);
}
__device__ inline float4 f4leaky(float4 a) {
    return make_float4(a.x > 0.f ? a.x : 0.2f * a.x, a.y > 0.f ? a.y : 0.2f * a.y,
                       a.z > 0.f ? a.z : 0.2f * a.z, a.w > 0.f ? a.w : 0.2f * a.w);
}
__device__ inline float f4dot(float4 a, float4 b) {
    return a.x * b.x + a.y * b.y + a.z * b.z + a.w * b.w;
}
__device__ inline float4 f4mix(float sc, float4 a, float p, float4 x) {
    return make_float4(fmaf(sc, a.x, p * x.x), fmaf(sc, a.y, p * x.y),
                       fmaf(sc, a.z, p * x.z), fmaf(sc, a.w, p * x.w));
}
__device__ inline float4 bfh2f4(bf16x8 v, int half) {
    int o = half * 4;
    return make_float4(bf2f(v[o]), bf2f(v[o + 1]), bf2f(v[o + 2]), bf2f(v[o + 3]));
}

// ---------------- CSR build (both edge types per dispatch) ----------------

__global__ __launch_bounds__(256) void count2_k(const int* __restrict__ dst0,
                                                const int* __restrict__ dst1,
                                                int* __restrict__ deg0,
                                                int* __restrict__ deg1) {
    int e = blockIdx.x * 256 + threadIdx.x;
    if (e < E_AA) atomicAdd(&deg0[dst0[e]], 1);
    if (e < E_AS) atomicAdd(&deg1[dst1[e]], 1);
}

// phase A: per-block sums of deg (two concatenated arrays)
__global__ __launch_bounds__(256) void scanA_k(const int* __restrict__ deg0, int n0,
                                               const int* __restrict__ deg1, int n1,
                                               int nb0, int* __restrict__ bsum) {
    int b = blockIdx.x;
    const int* deg; int n; int lb;
    if ((int)b < nb0) { deg = deg0; n = n0; lb = b; }
    else { deg = deg1; n = n1; lb = b - nb0; }
    int t = threadIdx.x;
    int base = lb * SCAN_CH + t * 8;
    int s = 0;
    #pragma unroll
    for (int i = 0; i < 8; ++i) { int idx = base + i; s += (idx < n) ? deg[idx] : 0; }
    int lane = t & 63, w = t >> 6;
    #pragma unroll
    for (int off = 1; off < 64; off <<= 1) {
        int u = __shfl_up(s, off, 64);
        if (lane >= off) s += u;
    }
    __shared__ int ws[4];
    if (lane == 63) ws[w] = s;
    __syncthreads();
    if (t == 0) bsum[blockIdx.x] = ws[0] + ws[1] + ws[2] + ws[3];
}

// phase B: exclusive-scan the block sums (two segments) in one wave
__global__ void scanB_k(int* __restrict__ bsum, int nb0, int nb1) {
    int t = threadIdx.x;   // 64
    int n = nb0 + nb1;
    int v = (t < n) ? bsum[t] : 0;
    int incl = v;
    #pragma unroll
    for (int off = 1; off < 64; off <<= 1) {
        int u = __shfl_up(incl, off, 64);
        if (t >= off) incl += u;
    }
    int excl = incl - v;
    int sum0 = __shfl(incl, nb0 - 1, 64);
    if (t >= nb0) excl -= sum0;
    if (t < n) bsum[t] = excl;
}

// phase C: block-local prefix + global offset -> row_start (exclusive), plus rs[n]
__global__ __launch_bounds__(256) void scanC_k(const int* __restrict__ deg0, int n0,
                                               const int* __restrict__ deg1, int n1,
                                               int nb0, const int* __restrict__ bsum,
                                               int* __restrict__ rs0, int* __restrict__ rs1) {
    int b = blockIdx.x;
    const int* deg; int n; int* rs; int lb;
    if ((int)b < nb0) { deg = deg0; n = n0; rs = rs0; lb = b; }
    else { deg = deg1; n = n1; rs = rs1; lb = b - nb0; }
    int boff = bsum[b];
    int t = threadIdx.x;
    int base = lb * SCAN_CH + t * 8;
    int v[8];
    int tsum = 0;
    #pragma unroll
    for (int i = 0; i < 8; ++i) {
        int idx = base + i;
        v[i] = (idx < n) ? deg[idx] : 0;
        tsum += v[i];
    }
    int lane = t & 63, w = t >> 6;
    int incl = tsum;
    #pragma unroll
    for (int off = 1; off < 64; off <<= 1) {
        int u = __shfl_up(incl, off, 64);
        if (lane >= off) incl += u;
    }
    __shared__ int ws[4];
    if (lane == 63) ws[w] = incl;
    __syncthreads();
    int woff = 0;
    for (int i = 0; i < w; ++i) woff += ws[i];
    int run = boff + woff + incl - tsum;
    #pragma unroll
    for (int i = 0; i < 8; ++i) {
        int idx = base + i;
        if (idx < n) {
            rs[idx] = run;
            run += v[i];
            if (idx == n - 1) rs[n] = run;
        }
    }
}

// scatter: build csr_src + CSR-ordered bf16 edge attrs (kills 1 gather hop in agg)
__global__ __launch_bounds__(256) void scatter2_k(
    const int* __restrict__ dst0, const int* __restrict__ src0, const float* __restrict__ ea0,
    const int* __restrict__ dst1, const int* __restrict__ src1, const float* __restrict__ ea1,
    const int* __restrict__ rs0, const int* __restrict__ rs1,
    int* __restrict__ cur0, int* __restrict__ cur1,
    int* __restrict__ csrsrc0, int* __restrict__ csrsrc1,
    short* __restrict__ eas0, short* __restrict__ eas1) {
    int e = blockIdx.x * 256 + threadIdx.x;
    if (e < E_AA) {
        int d = dst0[e];
        int pos = atomicAdd(&cur0[d], 1);
        int slot = rs0[d] + pos;
        csrsrc0[slot] = src0[e];
        float4 a = ((const float4*)ea0)[(size_t)e * 2];
        float4 b = ((const float4*)ea0)[(size_t)e * 2 + 1];
        bf16x8 pk;
        pk[0] = f2bf(a.x); pk[1] = f2bf(a.y); pk[2] = f2bf(a.z); pk[3] = f2bf(a.w);
        pk[4] = f2bf(b.x); pk[5] = f2bf(b.y); pk[6] = f2bf(b.z); pk[7] = f2bf(b.w);
        *(bf16x8*)(eas0 + (size_t)slot * 8) = pk;
    }
    if (e < E_AS) {
        int d = dst1[e];
        int pos = atomicAdd(&cur1[d], 1);
        int slot = rs1[d] + pos;
        csrsrc1[slot] = src1[e];
        float4 a = ((const float4*)ea1)[(size_t)e * 2];
        float4 b = ((const float4*)ea1)[(size_t)e * 2 + 1];
        bf16x8 pk;
        pk[0] = f2bf(a.x); pk[1] = f2bf(a.y); pk[2] = f2bf(a.z); pk[3] = f2bf(a.w);
        pk[4] = f2bf(b.x); pk[5] = f2bf(b.y); pk[6] = f2bf(b.z); pk[7] = f2bf(b.w);
        *(bf16x8*)(eas1 + (size_t)slot * 8) = pk;
    }
}

// ---- degree counting-sort (LDS hist, both node types per dispatch) ----

__global__ __launch_bounds__(256) void deghist2_k(const int* __restrict__ rs0, int n0,
                                                  const int* __restrict__ rs1, int n1,
                                                  int nb0, int* __restrict__ dh0,
                                                  int* __restrict__ dh1) {
    int b = blockIdx.x;
    const int* rs; int n; int* dh; int lb;
    if ((int)b < nb0) { rs = rs0; n = n0; dh = dh0; lb = b; }
    else { rs = rs1; n = n1; dh = dh1; lb = b - nb0; }
    __shared__ int lh[256];
    int t = threadIdx.x;
    lh[t] = 0;
    __syncthreads();
    int d = lb * 256 + t;
    if (d < n) {
        int deg = rs[d + 1] - rs[d];
        if (deg > 255) deg = 255;
        atomicAdd(&lh[deg], 1);
    }
    __syncthreads();
    if (lh[t]) atomicAdd(&dh[t], lh[t]);
}

__global__ void binscan2_k(const int* __restrict__ dh0, const int* __restrict__ dh1,
                           int* __restrict__ dbo0, int* __restrict__ dbo1) {
    int w = threadIdx.x >> 6, lane = threadIdx.x & 63;
    const int* dh = w ? dh1 : dh0;
    int* dbo = w ? dbo1 : dbo0;
    int v[4]; int s = 0;
    #pragma unroll
    for (int i = 0; i < 4; ++i) { v[i] = dh[lane * 4 + i]; s += v[i]; }
    int incl = s;
    #pragma unroll
    for (int off = 1; off < 64; off <<= 1) {
        int u = __shfl_up(incl, off, 64);
        if (lane >= off) incl += u;
    }
    int run = incl - s;
    #pragma unroll
    for (int i = 0; i < 4; ++i) { dbo[lane * 4 + i] = run; run += v[i]; }
}

__global__ __launch_bounds__(256) void degscatter2_k(const int* __restrict__ rs0, int n0,
                                                     const int* __restrict__ rs1, int n1,
                                                     int nb0,
                                                     const int* __restrict__ dbo0,
                                                     const int* __restrict__ dbo1,
                                                     int* __restrict__ dcur0,
                                                     int* __restrict__ dcur1,
                                                     int* __restrict__ perm0,
                                                     int* __restrict__ perm1) {
    int b = blockIdx.x;
    const int* rs; int n; const int* dbo; int* dcur; int* perm; int lb;
    if ((int)b < nb0) { rs = rs0; n = n0; dbo = dbo0; dcur = dcur0; perm = perm0; lb = b; }
    else { rs = rs1; n = n1; dbo = dbo1; dcur = dcur1; perm = perm1; lb = b - nb0; }
    __shared__ int lh[256];
    __shared__ int lbase[256];
    int t = threadIdx.x;
    lh[t] = 0;
    __syncthreads();
    int d = lb * 256 + t;
    int deg = 0, lpos = 0;
    if (d < n) {
        deg = rs[d + 1] - rs[d];
        if (deg > 255) deg = 255;
        lpos = atomicAdd(&lh[deg], 1);
    }
    __syncthreads();
    int cnt = lh[t];
    if (cnt) lbase[t] = atomicAdd(&dcur[t], cnt);
    __syncthreads();
    if (d < n) perm[dbo[deg] + lbase[deg] + lpos] = d;
}

// ---------------- converts: x_artist -> Xb, x_style -> Xsb (zero-padded) ----------------

__global__ __launch_bounds__(256) void cvt2_k(const float* __restrict__ xa,
                                              const float* __restrict__ xs,
                                              short* __restrict__ Xb,
                                              short* __restrict__ Xsb) {
    const int t4A = NAPAD * 32;
    const int t4S = NSPAD * 32;
    int i = blockIdx.x * 256 + threadIdx.x;
    if (i < t4A) {
        int row = i >> 5, c4 = i & 31;
        float4 v = make_float4(0.f, 0.f, 0.f, 0.f);
        if (row < NA) v = ((const float4*)xa)[(size_t)row * 32 + c4];
        short4 s;
        s.x = f2bf(v.x); s.y = f2bf(v.y); s.z = f2bf(v.z); s.w = f2bf(v.w);
        ((short4*)Xb)[i] = s;
    } else if (i < t4A + t4S) {
        int j = i - t4A;
        int row = j >> 5, c4 = j & 31;
        float4 v = make_float4(0.f, 0.f, 0.f, 0.f);
        if (row < NS && c4 < 16) v = ((const float4*)xs)[(size_t)row * 16 + c4];  // DIN_S=64
        short4 s;
        s.x = f2bf(v.x); s.y = f2bf(v.y); s.z = f2bf(v.z); s.w = f2bf(v.w);
        ((short4*)Xsb)[j] = s;
    }
}

// ---------------- all 12 weight transposes upfront: Wt[layer][w][n][k] bf16 ----------------

__global__ __launch_bounds__(256) void wtr12_k(
    const float* __restrict__ Wl0_aa, const float* __restrict__ Wr0_aa,
    const float* __restrict__ Wl0_as, const float* __restrict__ Wr0_as,
    const float* __restrict__ Wl_aa, const float* __restrict__ Wr_aa,
    const float* __restrict__ Wl_as, const float* __restrict__ Wr_as,
    short* __restrict__ Wt) {
    int mat = blockIdx.x >> 6;            // 0..11
    int layer = mat >> 2, w = mat & 3;
    int idx = (blockIdx.x & 63) * 256 + threadIdx.x;  // k*128+n
    int k = idx >> 7, n = idx & 127;
    const float* W;
    int K = 128;
    if (layer == 0) {
        W = (w == 0) ? Wl0_aa : (w == 1) ? Wr0_aa : (w == 2) ? Wl0_as : Wr0_as;
        if (w == 3) K = 64;
    } else {
        int j = layer - 1;
        W = ((w == 0) ? Wl_aa : (w == 1) ? Wr_aa : (w == 2) ? Wl_as : Wr_as)
            + (size_t)j * 16384;
    }
    float v = (k < K) ? W[(size_t)k * 128 + n] : 0.f;
    Wt[(size_t)mat * 16384 + n * 128 + k] = f2bf(v);
}

// ---------------- MFMA quad GEMM (all outputs bf16) ----------------

__global__ __launch_bounds__(256) void gemm4_k(
    const short* __restrict__ Xb, const short* __restrict__ Xsb,
    const short* __restrict__ Wt,
    short* __restrict__ Y0b, short* __restrict__ Y1b, short* __restrict__ Y2b,
    short* __restrict__ Y3b, int gM) {
    int t = threadIdx.x;
    int wave = t >> 6, lane = t & 63;
    int quad = lane >> 4, l16 = lane & 15;
    bool style = (int)blockIdx.x >= gM;
    int rblk = style ? (int)blockIdx.x - gM : (int)blockIdx.x;
    const short* X = style ? Xsb : Xb;
    int rbase = rblk * 64 + wave * 16;

    bf16x8 a[4];
    const short* arow = X + (size_t)(rbase + l16) * 128 + quad * 8;
    #pragma unroll
    for (int kb = 0; kb < 4; ++kb) a[kb] = *(const bf16x8*)(arow + kb * 32);

    if (!style) {
        short* Yp[3] = {Y0b, Y1b, Y2b};
        #pragma unroll
        for (int w = 0; w < 3; ++w) {
            const short* Wb = Wt + (size_t)w * 16384;
            #pragma unroll
            for (int nt = 0; nt < 8; ++nt) {
                f32x4 acc = {0.f, 0.f, 0.f, 0.f};
                const short* brow = Wb + (size_t)(nt * 16 + l16) * 128 + quad * 8;
                #pragma unroll
                for (int kb = 0; kb < 4; ++kb) {
                    bf16x8 b = *(const bf16x8*)(brow + kb * 32);
                    acc = __builtin_amdgcn_mfma_f32_16x16x32_bf16(a[kb], b, acc, 0, 0, 0);
                }
                int col = nt * 16 + l16;
                #pragma unroll
                for (int r = 0; r < 4; ++r) {
                    int row = rbase + quad * 4 + r;
                    if (row < NA) Yp[w][(size_t)row * 128 + col] = f2bf(acc[r]);
                }
            }
        }
    } else {
        const short* Wb = Wt + (size_t)3 * 16384;
        #pragma unroll
        for (int nt = 0; nt < 8; ++nt) {
            f32x4 acc = {0.f, 0.f, 0.f, 0.f};
            const short* brow = Wb + (size_t)(nt * 16 + l16) * 128 + quad * 8;
            #pragma unroll
            for (int kb = 0; kb < 4; ++kb) {
                bf16x8 b = *(const bf16x8*)(brow + kb * 32);
                acc = __builtin_amdgcn_mfma_f32_16x16x32_bf16(a[kb], b, acc, 0, 0, 0);
            }
            int col = nt * 16 + l16;
            #pragma unroll
            for (int r = 0; r < 4; ++r) {
                int row = rbase + quad * 4 + r;
                if (row < NS) Y3b[(size_t)row * 128 + col] = f2bf(acc[r]);
            }
        }
    }
}

// ---------------- fused GATv2 aggregation, AA + AS in one dispatch ----------------
// 4 dst/wave, 16 lanes/dst; xl/xr/eattr all bf16; CSR-ordered src+eattr (1 gather hop);
// LPT order (descending degree). launch_bounds (256,2): tighter caps spill (R6).

template<bool RELU>
__global__ __launch_bounds__(256, 2) void agg2_k(
    const short* __restrict__ xl0, const short* __restrict__ xr0,
    const short* __restrict__ eas0, const int* __restrict__ csrsrc0,
    const float* __restrict__ We0, const float* __restrict__ att0,
    const float* __restrict__ bias0, const int* __restrict__ rs0,
    const int* __restrict__ perm0,
    float* __restrict__ out0, short* __restrict__ outb0, int nd0, int nblk0,
    const short* __restrict__ xl1, const short* __restrict__ xr1,
    const short* __restrict__ eas1, const int* __restrict__ csrsrc1,
    const float* __restrict__ We1, const float* __restrict__ att1,
    const float* __restrict__ bias1, const int* __restrict__ rs1,
    const int* __restrict__ perm1,
    float* __restrict__ out1, short* __restrict__ outb1, int nd1) {

    const short* xl; const short* xrp; const short* eas; const int* csrsrc;
    const float* We; const float* att; const float* bias;
    const int* row_start; const int* perm;
    float* out; short* outb; int ndst, blk;
    if ((int)blockIdx.x < nblk0) {
        xl = xl0; xrp = xr0; eas = eas0; csrsrc = csrsrc0; We = We0; att = att0; bias = bias0;
        row_start = rs0; perm = perm0; out = out0; outb = outb0;
        ndst = nd0; blk = blockIdx.x;
    } else {
        xl = xl1; xrp = xr1; eas = eas1; csrsrc = csrsrc1; We = We1; att = att1; bias = bias1;
        row_start = rs1; perm = perm1; out = out1; outb = outb1;
        ndst = nd1; blk = blockIdx.x - nblk0;
    }

    int wave = threadIdx.x >> 6;
    int lane = threadIdx.x & 63;
    int g = lane >> 4;
    int sl = lane & 15;
    int c = sl * 8;

    int di = blk * 16 + wave * 4 + g;
    bool has = di < ndst;
    int d = has ? perm[ndst - 1 - di] : 0;    // LPT: heaviest dsts first

    float4 WeA[8], WeB[8];
    #pragma unroll
    for (int k = 0; k < 8; ++k) {
        WeA[k] = *(const float4*)(We + k * 128 + c);
        WeB[k] = *(const float4*)(We + k * 128 + c + 4);
    }
    float4 attA = *(const float4*)(att + c);
    float4 attB = *(const float4*)(att + c + 4);
    float4 bA = *(const float4*)(bias + c);
    float4 bB = *(const float4*)(bias + c + 4);
    bf16x8 xrb = *(const bf16x8*)(xrp + (size_t)d * 128 + c);
    float4 xrA = bfh2f4(xrb, 0), xrB = bfh2f4(xrb, 1);

    float4 accA = {0,0,0,0}, accB = {0,0,0,0};
    float den = 0.f, mrun = -INFINITY;

    int e0 = has ? row_start[d] : 0;
    int cnt = has ? row_start[d + 1] - e0 : 0;
    int last = (cnt > 0) ? e0 + cnt - 1 : 0;   // local clamp -> re-reads resident lines

    for (int i = 0; ; i += 4) {
        if (!__any(i < cnt)) break;

        int idx0 = e0 + i;
        int c0 = idx0 < last ? idx0 : last;
        int c1 = idx0 + 1 < last ? idx0 + 1 : last;
        int c2 = idx0 + 2 < last ? idx0 + 2 : last;
        int c3 = idx0 + 3 < last ? idx0 + 3 : last;
        int s0 = csrsrc[c0], s1 = csrsrc[c1], s2 = csrsrc[c2], s3 = csrsrc[c3];
        bf16x8 ea0 = *(const bf16x8*)(eas + (size_t)c0 * 8);
        bf16x8 ea1 = *(const bf16x8*)(eas + (size_t)c1 * 8);
        bf16x8 ea2 = *(const bf16x8*)(eas + (size_t)c2 * 8);
        bf16x8 ea3 = *(const bf16x8*)(eas + (size_t)c3 * 8);
        bf16x8 xb0 = *(const bf16x8*)(xl + (size_t)s0 * 128 + c);
        bf16x8 xb1 = *(const bf16x8*)(xl + (size_t)s1 * 128 + c);
        bf16x8 xb2 = *(const bf16x8*)(xl + (size_t)s2 * 128 + c);
        bf16x8 xb3 = *(const bf16x8*)(xl + (size_t)s3 * 128 + c);

        float4 x0A = bfh2f4(xb0, 0), x0B = bfh2f4(xb0, 1);
        float4 x1A = bfh2f4(xb1, 0), x1B = bfh2f4(xb1, 1);
        float4 x2A = bfh2f4(xb2, 0), x2B = bfh2f4(xb2, 1);
        float4 x3A = bfh2f4(xb3, 0), x3B = bfh2f4(xb3, 1);

        auto logit = [&](float4 xA, float4 xB, bf16x8 eab) -> float {
            float4 ea = bfh2f4(eab, 0), eb = bfh2f4(eab, 1);
            float4 mA = f4add(xA, xrA), mB = f4add(xB, xrB);
            mA = f4fma(ea.x, WeA[0], mA); mB = f4fma(ea.x, WeB[0], mB);
            mA = f4fma(ea.y, WeA[1], mA); mB = f4fma(ea.y, WeB[1], mB);
            mA = f4fma(ea.z, WeA[2], mA); mB = f4fma(ea.z, WeB[2], mB);
            mA = f4fma(ea.w, WeA[3], mA); mB = f4fma(ea.w, WeB[3], mB);
            mA = f4fma(eb.x, WeA[4], mA); mB = f4fma(eb.x, WeB[4], mB);
            mA = f4fma(eb.y, WeA[5], mA); mB = f4fma(eb.y, WeB[5], mB);
            mA = f4fma(eb.z, WeA[6], mA); mB = f4fma(eb.z, WeB[6], mB);
            mA = f4fma(eb.w, WeA[7], mA); mB = f4fma(eb.w, WeB[7], mB);
            return f4dot(f4leaky(mA), attA) + f4dot(f4leaky(mB), attB);
        };

        float t0 = logit(x0A, x0B, ea0);
        float t1 = logit(x1A, x1B, ea1);
        float t2 = logit(x2A, x2B, ea2);
        float t3 = logit(x3A, x3B, ea3);
        #pragma unroll
        for (int off = 8; off; off >>= 1) {
            t0 += __shfl_xor(t0, off, 64);
            t1 += __shfl_xor(t1, off, 64);
            t2 += __shfl_xor(t2, off, 64);
            t3 += __shfl_xor(t3, off, 64);
        }
        // invalidate tail edges (group-uniform)
        if (i + 1 >= cnt) t1 = -INFINITY;
        if (i + 2 >= cnt) t2 = -INFINITY;
        if (i + 3 >= cnt) t3 = -INFINITY;

        if (i < cnt) {   // at least t0 valid -> nm finite
            float m4 = fmaxf(fmaxf(t0, t1), fmaxf(t2, t3));
            float nm = fmaxf(mrun, m4);
            float sc = __expf(mrun - nm);     // mrun=-inf first time -> 0
            float p0 = __expf(t0 - nm);
            float p1 = __expf(t1 - nm);
            float p2 = __expf(t2 - nm);
            float p3 = __expf(t3 - nm);
            den = den * sc + p0 + p1 + p2 + p3;
            accA = f4mix(sc, accA, p0, x0A);
            accA = f4fma(p1, x1A, accA);
            accA = f4fma(p2, x2A, accA);
            accA = f4fma(p3, x3A, accA);
            accB = f4mix(sc, accB, p0, x0B);
            accB = f4fma(p1, x1B, accB);
            accB = f4fma(p2, x2B, accB);
            accB = f4fma(p3, x3B, accB);
            mrun = nm;
        }
    }

    float inv = 1.f / fmaxf(den, 1e-16f);
    float4 oA = make_float4(accA.x * inv + bA.x, accA.y * inv + bA.y,
                            accA.z * inv + bA.z, accA.w * inv + bA.w);
    float4 oB = make_float4(accB.x * inv + bB.x, accB.y * inv + bB.y,
                            accB.z * inv + bB.z, accB.w * inv + bB.w);
    if (RELU) {
        oA = make_float4(fmaxf(oA.x,0.f), fmaxf(oA.y,0.f), fmaxf(oA.z,0.f), fmaxf(oA.w,0.f));
        oB = make_float4(fmaxf(oB.x,0.f), fmaxf(oB.y,0.f), fmaxf(oB.z,0.f), fmaxf(oB.w,0.f));
    }
    float ss = f4dot(oA, oA) + f4dot(oB, oB);
    #pragma unroll
    for (int off = 8; off; off >>= 1) ss += __shfl_xor(ss, off, 64);
    float innv = 1.f / fmaxf(sqrtf(ss), 1e-12f);
    oA = make_float4(oA.x * innv, oA.y * innv, oA.z * innv, oA.w * innv);
    oB = make_float4(oB.x * innv, oB.y * innv, oB.z * innv, oB.w * innv);
    if (has) {
        if (out) {
            float4* op = (float4*)(out + (size_t)d * 128 + c);
            op[0] = oA;
            op[1] = oB;
        }
        if (outb) {
            bf16x8 pk;
            pk[0] = f2bf(oA.x); pk[1] = f2bf(oA.y); pk[2] = f2bf(oA.z); pk[3] = f2bf(oA.w);
            pk[4] = f2bf(oB.x); pk[5] = f2bf(oB.y); pk[6] = f2bf(oB.z); pk[7] = f2bf(oB.w);
            *(bf16x8*)(outb + (size_t)d * 128 + c) = pk;
        }
    }
}

// ---------------- launch ----------------

extern "C" void kernel_launch(void* const* d_in, const int* in_sizes, int n_in,
                              void* d_out, int out_size, void* d_ws, size_t ws_size,
                              hipStream_t stream) {
    const float* x_artist = (const float*)d_in[0];
    const float* x_style  = (const float*)d_in[1];
    const int*   src_aa   = (const int*)d_in[2];
    const int*   dst_aa   = (const int*)d_in[3];
    const float* eattr_aa = (const float*)d_in[4];
    const int*   src_as   = (const int*)d_in[5];
    const int*   dst_as   = (const int*)d_in[6];
    const float* eattr_as = (const float*)d_in[7];
    const float* Wl0_aa = (const float*)d_in[8];
    const float* Wr0_aa = (const float*)d_in[9];
    const float* att0_aa = (const float*)d_in[10];
    const float* We0_aa = (const float*)d_in[11];
    const float* b0_aa = (const float*)d_in[12];
    const float* Wl0_as = (const float*)d_in[13];
    const float* Wr0_as = (const float*)d_in[14];
    const float* att0_as = (const float*)d_in[15];
    const float* We0_as = (const float*)d_in[16];
    const float* b0_as = (const float*)d_in[17];
    const float* Wl_aa = (const float*)d_in[18];
    const float* Wr_aa = (const float*)d_in[19];
    const float* att_aa = (const float*)d_in[20];
    const float* We_aa = (const float*)d_in[21];
    const float* b_aa = (const float*)d_in[22];
    const float* Wl_as = (const float*)d_in[23];
    const float* Wr_as = (const float*)d_in[24];
    const float* att_as = (const float*)d_in[25];
    const float* We_as = (const float*)d_in[26];
    const float* b_as = (const float*)d_in[27];

    float* out = (float*)d_out;

    // ws layout: bf16 regions, then int regions
    short* Xb    = (short*)d_ws;                       // [NAPAD][128]
    short* Xsb   = Xb + (size_t)NAPAD * 128;           // [NSPAD][128]
    short* Wt    = Xsb + (size_t)NSPAD * 128;          // [3][4][128][128]
    short* bufAb = Wt + 12 * 16384;                    // xl_aa
    short* bufDb = bufAb + (size_t)NA * 128;           // xl_as
    short* bufBb = bufDb + (size_t)NA * 128;           // xr_aa
    short* bufCb = bufBb + (size_t)NA * 128;           // xr_as
    short* easAA = bufCb + (size_t)NSPAD * 128;        // [E_AA][8]
    short* easAS = easAA + (size_t)E_AA * 8;           // [E_AS][8]
    int* ip = (int*)(easAS + (size_t)E_AS * 8);
    // zeroed zone
    int* zbase  = ip;
    int* deg_aa = ip;            ip += NA;
    int* cur_aa = ip;            ip += NA;
    int* deg_as = ip;            ip += NS;
    int* cur_as = ip;            ip += NS;
    int* dh_aa  = ip;            ip += 256;
    int* dh_as  = ip;            ip += 256;
    int* dcur_aa = ip;           ip += 256;
    int* dcur_as = ip;           ip += 256;
    size_t zbytes = (size_t)(ip - zbase) * sizeof(int);
    // non-zeroed
    int* rs_aa  = ip;            ip += NA + 1;
    int* rs_as  = ip;            ip += NS + 1;
    int* csrsrc_aa = ip;         ip += E_AA;
    int* csrsrc_as = ip;         ip += E_AS;
    int* perm_aa = ip;           ip += NA;
    int* perm_as = ip;           ip += NS;
    int* dbo_aa = ip;            ip += 256;
    int* dbo_as = ip;            ip += 256;
    int* bsum   = ip;            ip += 64;

    const int nbA_scan = (NA + SCAN_CH - 1) / SCAN_CH;
    const int nbS_scan = (NS + SCAN_CH - 1) / SCAN_CH;
    const int nbA_node = (NA + 255) / 256;
    const int nbS_node = (NS + 255) / 256;
    const int gE = (E_AA + 255) / 256;

    // ---- preprocessing ----
    hipMemsetAsync(zbase, 0, zbytes, stream);
    count2_k<<<gE, 256, 0, stream>>>(dst_aa, dst_as, deg_aa, deg_as);
    scanA_k<<<nbA_scan + nbS_scan, 256, 0, stream>>>(deg_aa, NA, deg_as, NS, nbA_scan, bsum);
    scanB_k<<<1, 64, 0, stream>>>(bsum, nbA_scan, nbS_scan);
    scanC_k<<<nbA_scan + nbS_scan, 256, 0, stream>>>(deg_aa, NA, deg_as, NS, nbA_scan,
                                                     bsum, rs_aa, rs_as);
    scatter2_k<<<gE, 256, 0, stream>>>(dst_aa, src_aa, eattr_aa,
                                       dst_as, src_as, eattr_as,
                                       rs_aa, rs_as, cur_aa, cur_as,
                                       csrsrc_aa, csrsrc_as, easAA, easAS);
    deghist2_k<<<nbA_node + nbS_node, 256, 0, stream>>>(rs_aa, NA, rs_as, NS, nbA_node,
                                                        dh_aa, dh_as);
    binscan2_k<<<1, 128, 0, stream>>>(dh_aa, dh_as, dbo_aa, dbo_as);
    degscatter2_k<<<nbA_node + nbS_node, 256, 0, stream>>>(rs_aa, NA, rs_as, NS, nbA_node,
                                                           dbo_aa, dbo_as, dcur_aa, dcur_as,
                                                           perm_aa, perm_as);
    cvt2_k<<<(NAPAD * 32 + NSPAD * 32 + 255) / 256, 256, 0, stream>>>(x_artist, x_style,
                                                                      Xb, Xsb);
    wtr12_k<<<12 * 64, 256, 0, stream>>>(Wl0_aa, Wr0_aa, Wl0_as, Wr0_as,
                                         Wl_aa, Wr_aa, Wl_as, Wr_as, Wt);

    const int gM = NAPAD / 64;        // 782
    const int gS4 = NSPAD / 64;       // 79
    const int aggA = (NA + 15) / 16;  // 3125
    const int aggS = (NS + 15) / 16;  // 313

    for (int layer = 0; layer < 3; ++layer) {
        int j = layer - 1;
        const float *patt_aa, *pWe_aa, *pb_aa, *patt_as, *pWe_as, *pb_as;
        if (layer == 0) {
            patt_aa = att0_aa; pWe_aa = We0_aa; pb_aa = b0_aa;
            patt_as = att0_as; pWe_as = We0_as; pb_as = b0_as;
        } else {
            patt_aa = att_aa + (size_t)j * CDIM;
            pWe_aa = We_aa + (size_t)j * ED * CDIM;
            pb_aa = b_aa + (size_t)j * CDIM;
            patt_as = att_as + (size_t)j * CDIM;
            pWe_as = We_as + (size_t)j * ED * CDIM;
            pb_as = b_as + (size_t)j * CDIM;
        }
        const short* pWt = Wt + (size_t)layer * 4 * 16384;
        float* hA_out = (layer == 2) ? out : nullptr;
        float* hS_out = (layer == 2) ? out + (size_t)NA * CDIM : nullptr;
        short* hA_outb = (layer == 2) ? nullptr : Xb;
        short* hS_outb = (layer == 2) ? nullptr : Xsb;

        gemm4_k<<<gM + gS4, 256, 0, stream>>>(Xb, Xsb, pWt, bufAb, bufBb, bufDb, bufCb, gM);

        if (layer < 2)
            agg2_k<true><<<aggA + aggS, 256, 0, stream>>>(
                bufAb, bufBb, easAA, csrsrc_aa, pWe_aa, patt_aa, pb_aa,
                rs_aa, perm_aa, hA_out, hA_outb, NA, aggA,
                bufDb, bufCb, easAS, csrsrc_as, pWe_as, patt_as, pb_as,
                rs_as, perm_as, hS_out, hS_outb, NS);
        else
            agg2_k<false><<<aggA + aggS, 256, 0, stream>>>(
                bufAb, bufBb, easAA, csrsrc_aa, pWe_aa, patt_aa, pb_aa,
                rs_aa, perm_aa, hA_out, hA_outb, NA, aggA,
                bufDb, bufCb, easAS, csrsrc_as, pWe_as, patt_as, pb_as,
                rs_as, perm_as, hS_out, hS_outb, NS);
    }
}